// Round 1
// 3111.729 us; speedup vs baseline: 4.5283x; 4.5283x over previous
//
#include <hip/hip_runtime.h>

#define B_    2
#define NSEQ  4096
#define DM    1024
#define H_    16
#define DH    64
#define MF    266
#define MP    272          // padded feature count (pads are zero)
#define NROWS (B_*NSEQ)    // 8192
#define NHROWS (B_*H_*NSEQ) // 131072
#define RATIO 0.06131393394849658f   // 266^-0.5
#define DNORM 0.3535533905932738f    // 64^-0.25
#define KEPS  1e-4f
#define CEPS  1e-6f

// chunked causal scan geometry
#define CH    256                 // tokens per chunk
#define NC    16                  // chunks per (b,h) = NSEQ/CH
#define MD    (MP*DH)             // 17408 state elements per (b,h)

typedef unsigned short u16;
typedef unsigned int   u32;

typedef __bf16 bf16x8 __attribute__((ext_vector_type(8)));
typedef float  f32x4  __attribute__((ext_vector_type(4)));

__device__ __forceinline__ float b2f(u16 u){ u32 x = ((u32)u) << 16; return __builtin_bit_cast(float, x); }
__device__ __forceinline__ float b2f_lo(u32 w){ return __builtin_bit_cast(float, w << 16); }
__device__ __forceinline__ float b2f_hi(u32 w){ return __builtin_bit_cast(float, w & 0xffff0000u); }
__device__ __forceinline__ u16 f2b(float f){
    u32 x = __builtin_bit_cast(u32, f);
    u32 r = x + 0x7fffu + ((x >> 16) & 1u);
    return (u16)(r >> 16);
}
__device__ __forceinline__ u32 enc_max(float f){ u32 b = __builtin_bit_cast(u32, f); return (b & 0x80000000u) ? ~b : (b | 0x80000000u); }
__device__ __forceinline__ float dec_max(u32 u){ u32 b = (u & 0x80000000u) ? (u & 0x7fffffffu) : ~u; return __builtin_bit_cast(float, b); }

// ---------------------------------------------------------------------------
// Per-input dtype detection (robust to either dtype). flag 1=bf16, 0=fp32.
// ---------------------------------------------------------------------------
__global__ void detect_kernel(const u32* __restrict__ src, int nwords,
                              u32* __restrict__ flag)
{
    __shared__ int cnt[256];
    int t = threadIdx.x; int c = 0;
    for (int i = t; i < nwords; i += 256) {
        u32 w = src[i];
        int ea = (int)((w >> 7)  & 0xFF);
        int eb = (int)((w >> 23) & 0xFF);
        c += (ea >= 112 && ea <= 143) ? 1 : 0;
        c += (eb >= 112 && eb <= 143) ? 1 : 0;
    }
    cnt[t] = c; __syncthreads();
    for (int s = 128; s; s >>= 1) { if (t < s) cnt[t] += cnt[t + s]; __syncthreads(); }
    if (t == 0) *flag = (cnt[0] >= (nwords * 3) / 2) ? 1u : 0u;  // 75% of 2*nwords
}

// ---------------------------------------------------------------------------
// Convert n elements (n % 8 == 0) from src (fp32 or bf16 per its flag) to bf16.
// ---------------------------------------------------------------------------
__global__ __launch_bounds__(256)
void conv_kernel(const void* __restrict__ src, u16* __restrict__ dst, int n,
                 const u32* __restrict__ gflag)
{
    int i = (blockIdx.x * 256 + threadIdx.x) * 8;
    if (i >= n) return;
    if (*gflag) {
        *(uint4*)(dst + i) = *(const uint4*)((const u16*)src + i);
    } else {
        const float* s = (const float*)src + i;
        u16 tmp[8];
        #pragma unroll
        for (int j = 0; j < 8; ++j) tmp[j] = f2b(s[j]);
        *(uint4*)(dst + i) = *(uint4*)tmp;
    }
}

// ---------------------------------------------------------------------------
// GEMM (reference-literal): C[r][c] = sum_k A[r][k] * W[c][k] + bias[c]
// (x @ W.T, W stored [out][in]). 128x128 tile, 4 waves, 16x16x32 bf16 MFMA.
// OUT_BF16: 0 -> fp32 C, 1 -> bf16 C.
// ---------------------------------------------------------------------------
template<int OUT_BF16>
__global__ __launch_bounds__(256)
void gemm_nt(const u16* __restrict__ A, const u16* __restrict__ Bm,
             const u16* __restrict__ bias, void* __restrict__ C)
{
    const int K = DM, Nc = DM;
    __shared__ u16 As[128][40];
    __shared__ u16 Bs[128][40];
    int t = threadIdx.x;
    int wave = t >> 6, lane = t & 63;
    int wm = wave >> 1, wn = wave & 1;
    int quad = lane >> 4, l16 = lane & 15;
    int bm = blockIdx.x * 128, bn = blockIdx.y * 128;
    f32x4 acc[4][4];
    #pragma unroll
    for (int i = 0; i < 4; ++i)
        #pragma unroll
        for (int j = 0; j < 4; ++j) acc[i][j] = (f32x4){0.f,0.f,0.f,0.f};

    for (int k0 = 0; k0 < K; k0 += 32) {
        #pragma unroll
        for (int it = 0; it < 2; ++it) {
            int L = t + it * 256;
            int r = L >> 2, c = (L & 3) * 8;
            *(uint4*)&As[r][c] = *(const uint4*)(A + (size_t)(bm + r) * K + k0 + c);
            *(uint4*)&Bs[r][c] = *(const uint4*)(Bm + (size_t)(bn + r) * K + k0 + c);
        }
        __syncthreads();
        bf16x8 af[4], bfr[4];
        #pragma unroll
        for (int i = 0; i < 4; ++i) {
            af[i]  = *(const bf16x8*)&As[wm*64 + i*16 + l16][quad*8];
            bfr[i] = *(const bf16x8*)&Bs[wn*64 + i*16 + l16][quad*8];
        }
        #pragma unroll
        for (int i = 0; i < 4; ++i)
            #pragma unroll
            for (int j = 0; j < 4; ++j)
                acc[i][j] = __builtin_amdgcn_mfma_f32_16x16x32_bf16(af[i], bfr[j], acc[i][j], 0, 0, 0);
        __syncthreads();
    }
    #pragma unroll
    for (int i = 0; i < 4; ++i) {
        #pragma unroll
        for (int j = 0; j < 4; ++j) {
            int col = bn + wn*64 + j*16 + l16;
            float bv = b2f(bias[col]);
            #pragma unroll
            for (int r = 0; r < 4; ++r) {
                int row = bm + wm*64 + i*16 + quad*4 + r;
                float v = acc[i][j][r] + bv;
                if (OUT_BF16) ((u16*)C)[(size_t)row * Nc + col] = f2b(v);
                else          ((float*)C)[(size_t)row * Nc + col] = v;
            }
        }
    }
}

// ---------------------------------------------------------------------------
// prep2: projC[m][d] = bf16(proj[m][d]) (per-input flag); zero gpart/gmax.
// ---------------------------------------------------------------------------
__global__ __launch_bounds__(256)
void prep2(const void* __restrict__ proj, u16* __restrict__ projC,
           u32* __restrict__ gpart, u32* __restrict__ gmax,
           const u32* __restrict__ gflag)
{
    int i = blockIdx.x * 256 + threadIdx.x;
    if (i < 256) gpart[i] = 0u;
    if (i == 256) *gmax = 0u;
    if (i < MF * DH) {
        projC[i] = (*gflag) ? ((const u16*)proj)[i]
                            : f2b(((const float*)proj)[i]);
    }
}

// ---------------------------------------------------------------------------
// Feature map (per-row block). MODE 0: Q. MODE 1: K global-max. MODE 2: K.
// ---------------------------------------------------------------------------
template<int MODE>
__global__ __launch_bounds__(256)
void feat_simple(const float* __restrict__ X, const u16* __restrict__ projC,
                 u16* __restrict__ OutP, u32* __restrict__ gpart,
                 const u32* __restrict__ gmax)
{
    int rid = blockIdx.x;
    int bh = rid >> 12, n = rid & 4095, b = bh >> 4, h = bh & 15;
    int t = threadIdx.x;
    __shared__ float dnS[64];
    __shared__ float red[256];
    if (t < 64) dnS[t] = X[((size_t)(b * NSEQ + n)) * DM + h * DH + t] * DNORM;
    __syncthreads();
    float diag = 0.f;
    #pragma unroll
    for (int d2 = 0; d2 < 64; ++d2) diag += dnS[d2] * dnS[d2];
    diag *= 0.5f;

    float dd1, dd2 = -3.4e38f;
    {
        const u16* pr = projC + (size_t)t * DH;
        float s = 0.f;
        #pragma unroll
        for (int d2 = 0; d2 < 64; ++d2) s += dnS[d2] * b2f(pr[d2]);
        dd1 = s;
    }
    if (t < MF - 256) {
        const u16* pr = projC + (size_t)(t + 256) * DH;
        float s = 0.f;
        #pragma unroll
        for (int d2 = 0; d2 < 64; ++d2) s += dnS[d2] * b2f(pr[d2]);
        dd2 = s;
    }
    red[t] = fmaxf(dd1, dd2);
    __syncthreads();
    for (int s2 = 128; s2; s2 >>= 1) {
        if (t < s2) red[t] = fmaxf(red[t], red[t + s2]);
        __syncthreads();
    }
    float rmax = red[0];

    if (MODE == 1) {
        if (t == 0) atomicMax(&gpart[blockIdx.x & 255], enc_max(rmax));
        return;
    }
    float stab = (MODE == 0) ? rmax : dec_max(*gmax);
    u16* orow = OutP + (size_t)rid * MP;
    orow[t] = f2b(RATIO * (__expf(dd1 - diag - stab) + KEPS));
    if (t < MF - 256)
        orow[t + 256] = f2b(RATIO * (__expf(dd2 - diag - stab) + KEPS));
    if (t >= MF - 256 && t < MP - 256)
        orow[t + 256] = 0;
}

__global__ void gmax_reduce(const u32* __restrict__ gpart, u32* __restrict__ gmax)
{
    __shared__ u32 r[256];
    int t = threadIdx.x;
    r[t] = gpart[t]; __syncthreads();
    for (int s = 128; s; s >>= 1) { if (t < s) r[t] = max(r[t], r[t + s]); __syncthreads(); }
    if (t == 0) *gmax = r[0];
}

// ---------------------------------------------------------------------------
// Chunk-parallel causal scan (3 phases).
// Lane layout (all 3 scan kernels): block = 4 waves; wave w owns d in
// [w*16, w*16+16); within a wave, lane = (mg, dl): mg = quad owns features
// m in [mg*68, mg*68+68), dl selects d = w*16+dl. Feature-reduction is
// intra-wave (shfl_xor 16/32) -> no reduce barrier.
// ---------------------------------------------------------------------------

// Phase A: per-chunk local sums S_c[m][d] = sum_{n in chunk} k'[m]*v[d],
//          z_c[m] = sum k'[m].  grid = B*H*NC = 512.
__global__ __launch_bounds__(256)
void chunk_sums(const u16* __restrict__ Kp, const u16* __restrict__ Vb,
                float* __restrict__ Sloc, float* __restrict__ zloc)
{
    int bhc = blockIdx.x;
    int bh = bhc >> 4, c = bhc & (NC - 1);
    int b = bh >> 4, h = bh & 15;
    int t = threadIdx.x;
    int w = t >> 6, mg = (t >> 4) & 3, dl = t & 15;
    int d = w * 16 + dl, m0 = mg * 68, base = mg * 34;

    __shared__ u32 sb[2][168];   // k (136 dwords) + v (32 dwords)

    float ctx[68], zl[68];
    #pragma unroll
    for (int j = 0; j < 68; ++j) { ctx[j] = 0.f; zl[j] = 0.f; }

    int n0 = c * CH;
    const u32* kr = (const u32*)(Kp + ((size_t)bh * NSEQ + n0) * MP);
    const u32* vr = (const u32*)(Vb + ((size_t)(b * NSEQ + n0)) * DM + h * DH);

    {   // prologue stage token 0
        if (t < 136)      sb[0][t] = kr[t];
        else if (t < 168) sb[0][t] = vr[t - 136];
    }
    __syncthreads();

    for (int ni = 0; ni < CH; ++ni) {
        int cur = ni & 1;
        u32 pf = 0;
        if (ni < CH - 1) {   // issue next-token loads early (latency hides under FMAs)
            const u32* kn = kr + (size_t)(ni + 1) * 136;
            const u32* vn = vr + (size_t)(ni + 1) * 512;
            if (t < 136)      pf = kn[t];
            else if (t < 168) pf = vn[t - 136];
        }
        const u32* kb = sb[cur];
        float vv = b2f(((const u16*)(sb[cur] + 136))[d]);
        #pragma unroll
        for (int j = 0; j < 34; ++j) {
            u32 kw = kb[base + j];
            float k0 = b2f_lo(kw), k1 = b2f_hi(kw);
            int j2 = j * 2;
            ctx[j2]     += k0 * vv;  zl[j2]     += k0;
            ctx[j2 + 1] += k1 * vv;  zl[j2 + 1] += k1;
        }
        if (ni < CH - 1 && t < 168) sb[cur ^ 1][t] = pf;
        __syncthreads();
    }

    size_t sbase = (size_t)bhc * MD;
    #pragma unroll
    for (int j = 0; j < 68; ++j)
        Sloc[sbase + (size_t)(m0 + j) * 64 + d] = ctx[j];
    if (w == 0 && dl == 0) {
        #pragma unroll
        for (int j = 0; j < 68; ++j)
            zloc[(size_t)bhc * MP + m0 + j] = zl[j];
    }
}

// Phase B: in-place exclusive prefix over chunks, per (b,h).
// grid = (32*MD)/256 = 2176 blocks exactly.
__global__ __launch_bounds__(256)
void chunk_prefix(float* __restrict__ Sloc, float* __restrict__ zloc)
{
    int gid = blockIdx.x * 256 + threadIdx.x;
    {
        int bh = gid / MD, e = gid - bh * MD;
        float run = 0.f;
        #pragma unroll
        for (int c = 0; c < NC; ++c) {
            size_t o = ((size_t)(bh * NC + c)) * MD + e;
            float v = Sloc[o]; Sloc[o] = run; run += v;
        }
    }
    if (gid < B_ * H_ * MP) {
        int bh = gid / MP, m = gid - bh * MP;
        float run = 0.f;
        #pragma unroll
        for (int c = 0; c < NC; ++c) {
            size_t o = ((size_t)(bh * NC + c)) * MP + m;
            float v = zloc[o]; zloc[o] = run; run += v;
        }
    }
}

// Phase C: rescan each chunk from its carry. grid = 512.
__global__ __launch_bounds__(256)
void scan_chunk(const u16* __restrict__ Qp, const u16* __restrict__ Kp,
                const u16* __restrict__ Vb, const float* __restrict__ Scar,
                const float* __restrict__ zcar, u16* __restrict__ attn)
{
    int bhc = blockIdx.x;
    int bh = bhc >> 4, c = bhc & (NC - 1);
    int b = bh >> 4, h = bh & 15;
    int t = threadIdx.x;
    int w = t >> 6, mg = (t >> 4) & 3, dl = t & 15;
    int d = w * 16 + dl, m0 = mg * 68, base = mg * 34;

    __shared__ u32 sb[2][304];   // q (136) + k (136) + v (32) dwords

    float ctx[68], zl[68];
    size_t sbase = (size_t)bhc * MD;
    #pragma unroll
    for (int j = 0; j < 68; ++j)
        ctx[j] = Scar[sbase + (size_t)(m0 + j) * 64 + d];
    #pragma unroll
    for (int j = 0; j < 68; ++j)
        zl[j] = zcar[(size_t)bhc * MP + m0 + j];

    int n0 = c * CH;
    const u32* qr = (const u32*)(Qp + ((size_t)bh * NSEQ + n0) * MP);
    const u32* kr = (const u32*)(Kp + ((size_t)bh * NSEQ + n0) * MP);
    const u32* vr = (const u32*)(Vb + ((size_t)(b * NSEQ + n0)) * DM + h * DH);
    u16* arow = attn + ((size_t)(b * NSEQ + n0)) * DM + h * DH + d;

    // slot0 (all t): t<136 -> q[t], else k[t-136] (covers k[0..119])
    // slot1 (t<48): t<16 -> k[t+120], else v[t-16]
    {
        sb[0][t] = (t < 136) ? qr[t] : kr[t - 136];
        if (t < 48) sb[0][t + 256] = (t < 16) ? kr[t + 120] : vr[t - 16];
    }
    __syncthreads();

    for (int ni = 0; ni < CH; ++ni) {
        int cur = ni & 1;
        u32 pf0 = 0, pf1 = 0;
        if (ni < CH - 1) {   // issue next-token loads early
            const u32* qn = qr + (size_t)(ni + 1) * 136;
            const u32* kn = kr + (size_t)(ni + 1) * 136;
            const u32* vn = vr + (size_t)(ni + 1) * 512;
            pf0 = (t < 136) ? qn[t] : kn[t - 136];
            if (t < 48) pf1 = (t < 16) ? kn[t + 120] : vn[t - 16];
        }

        const u32* qb = sb[cur];
        const u32* kb = sb[cur] + 136;
        float vv = b2f(((const u16*)(sb[cur] + 272))[d]);
        float np0 = 0.f, np1 = 0.f, dp0 = 0.f, dp1 = 0.f, sq0 = 0.f, sq1 = 0.f;
        #pragma unroll
        for (int j = 0; j < 34; ++j) {
            u32 kw = kb[base + j], qw = qb[base + j];
            float k0 = b2f_lo(kw), k1 = b2f_hi(kw);
            float q0 = b2f_lo(qw), q1 = b2f_hi(qw);
            int j2 = j * 2;
            ctx[j2]     += k0 * vv;  zl[j2]     += k0;
            np0 += q0 * ctx[j2];     dp0 += q0 * zl[j2];     sq0 += q0;
            ctx[j2 + 1] += k1 * vv;  zl[j2 + 1] += k1;
            np1 += q1 * ctx[j2 + 1]; dp1 += q1 * zl[j2 + 1]; sq1 += q1;
        }
        float num = np0 + np1;
        float den = dp0 + dp1 + CEPS * (sq0 + sq1);
        num += __shfl_xor(num, 16, 64);
        den += __shfl_xor(den, 16, 64);
        num += __shfl_xor(num, 32, 64);
        den += __shfl_xor(den, 32, 64);

        if (ni < CH - 1) {
            sb[cur ^ 1][t] = pf0;
            if (t < 48) sb[cur ^ 1][t + 256] = pf1;
        }
        if (mg == 0) arow[(size_t)ni * DM] = f2b(num / den);
        __syncthreads();
    }
}

// ---------------------------------------------------------------------------
extern "C" void kernel_launch(void* const* d_in, const int* in_sizes, int n_in,
                              void* d_out, int out_size, void* d_ws, size_t ws_size,
                              hipStream_t stream)
{
    (void)n_in; (void)out_size; (void)ws_size;
    // dict order: x, Wq, bq, Wk, bk, Wv, bv, Wo, bo, proj (sizes verified r4/r5)
    const void* x  = d_in[0];
    const void* Wq = d_in[1]; const void* bq = d_in[2];
    const void* Wk = d_in[3]; const void* bk = d_in[4];
    const void* Wv = d_in[5]; const void* bv = d_in[6];
    const void* Wo = d_in[7]; const void* bo = d_in[8];
    const void* proj = d_in[9];

    char* ws = (char*)d_ws;
    size_t off = 0;
    auto alloc = [&](size_t bytes) -> char* {
        char* p = ws + off; off += (bytes + 255) & ~(size_t)255; return p;
    };
    float* QKf  = (float*)alloc((size_t)NROWS * DM * 4);
    u16*   Vb   = (u16*)alloc((size_t)NROWS * DM * 2);
    u16*   Qp   = (u16*)alloc((size_t)NHROWS * MP * 2);
    u16*   Kp   = (u16*)alloc((size_t)NHROWS * MP * 2);
    u16*   projC= (u16*)alloc((size_t)MF * DH * 2);
    u16*   Wb   = (u16*)alloc((size_t)DM * DM * 2);
    u16*   bqb  = (u16*)alloc(DM * 2);
    u16*   bkb  = (u16*)alloc(DM * 2);
    u16*   bvb  = (u16*)alloc(DM * 2);
    u16*   bob  = (u16*)alloc(DM * 2);
    u32*   flags= (u32*)alloc(16 * 4);
    u32*   gmax = (u32*)alloc(256);
    u32*   gpart= (u32*)alloc(256 * 4);
    char*  xatt = alloc((size_t)NROWS * DM * 2);
    u16*   xb   = (u16*)xatt;    // alias: xb dead after gemm K
    u16*   attn = (u16*)xatt;    // scan writes afterwards
    // chunk-scan carry state (35.7 MB + 0.6 MB)
    float* Sloc = (float*)alloc((size_t)(B_ * H_ * NC) * MD * 4);
    float* zloc = (float*)alloc((size_t)(B_ * H_ * NC) * MP * 4);

    const int nW = DM * DM, nX = NROWS * DM;
    dim3 gg(NROWS / 128, DM / 128);

    for (int i = 0; i < 10; ++i) {
        int n = in_sizes[i];
        int nwords = n / 2; if (nwords > 4096) nwords = 4096;
        detect_kernel<<<1, 256, 0, stream>>>((const u32*)d_in[i], nwords, flags + i);
    }

    prep2<<<(MF * DH + 255) / 256, 256, 0, stream>>>(proj, projC, gpart, gmax, flags + 9);
    conv_kernel<<<(nX + 2047) / 2048, 256, 0, stream>>>(x, xb, nX, flags + 0);
    conv_kernel<<<1, 256, 0, stream>>>(bq, bqb, DM, flags + 2);
    conv_kernel<<<1, 256, 0, stream>>>(bk, bkb, DM, flags + 4);
    conv_kernel<<<1, 256, 0, stream>>>(bv, bvb, DM, flags + 6);
    conv_kernel<<<1, 256, 0, stream>>>(bo, bob, DM, flags + 8);

    conv_kernel<<<(nW + 2047) / 2048, 256, 0, stream>>>(Wv, Wb, nW, flags + 5);
    gemm_nt<1><<<gg, 256, 0, stream>>>(xb, Wb, bvb, Vb);

    conv_kernel<<<(nW + 2047) / 2048, 256, 0, stream>>>(Wq, Wb, nW, flags + 1);
    gemm_nt<0><<<gg, 256, 0, stream>>>(xb, Wb, bqb, QKf);
    feat_simple<0><<<NHROWS, 256, 0, stream>>>(QKf, projC, Qp, gpart, gmax);

    conv_kernel<<<(nW + 2047) / 2048, 256, 0, stream>>>(Wk, Wb, nW, flags + 3);
    gemm_nt<0><<<gg, 256, 0, stream>>>(xb, Wb, bkb, QKf);
    feat_simple<1><<<NHROWS, 256, 0, stream>>>(QKf, projC, Kp, gpart, gmax);
    gmax_reduce<<<1, 256, 0, stream>>>(gpart, gmax);
    feat_simple<2><<<NHROWS, 256, 0, stream>>>(QKf, projC, Kp, gpart, gmax);

    // chunk-parallel causal scan: local sums -> exclusive prefix -> rescan
    chunk_sums<<<B_ * H_ * NC, 256, 0, stream>>>(Kp, Vb, Sloc, zloc);
    chunk_prefix<<<(B_ * H_ * MD) / 256, 256, 0, stream>>>(Sloc, zloc);
    scan_chunk<<<B_ * H_ * NC, 256, 0, stream>>>(Qp, Kp, Vb, Sloc, zloc, attn);

    conv_kernel<<<(nW + 2047) / 2048, 256, 0, stream>>>(Wo, Wb, nW, flags + 7);
    // OUTPUT IS FP32 (reference's output dtype, per harness instructions).
    gemm_nt<0><<<gg, 256, 0, stream>>>(attn, Wb, bob, d_out);
}

// Round 3
// 971.640 us; speedup vs baseline: 14.5022x; 3.2026x over previous
//
#include <hip/hip_runtime.h>

#define B_    2
#define NSEQ  4096
#define DM    1024
#define H_    16
#define DH    64
#define MF    266
#define MP    272          // padded feature count (pads are zero)
#define NROWS (B_*NSEQ)    // 8192
#define NHROWS (B_*H_*NSEQ) // 131072
#define RATIO 0.06131393394849658f   // 266^-0.5
#define DNORM 0.3535533905932738f    // 64^-0.25
#define KEPS  1e-4f
#define CEPS  1e-6f

// chunked causal scan geometry
#define CH    256                 // tokens per chunk
#define NC    16                  // chunks per (b,h) = NSEQ/CH
#define MD    (MP*DH)             // 17408 state elements per (b,h)

typedef unsigned short u16;
typedef unsigned int   u32;

typedef __bf16 bf16x8 __attribute__((ext_vector_type(8)));
typedef float  f32x4  __attribute__((ext_vector_type(4)));

__device__ __forceinline__ float b2f(u16 u){ u32 x = ((u32)u) << 16; return __builtin_bit_cast(float, x); }
__device__ __forceinline__ float b2f_lo(u32 w){ return __builtin_bit_cast(float, w << 16); }
__device__ __forceinline__ float b2f_hi(u32 w){ return __builtin_bit_cast(float, w & 0xffff0000u); }
__device__ __forceinline__ u16 f2b(float f){
    u32 x = __builtin_bit_cast(u32, f);
    u32 r = x + 0x7fffu + ((x >> 16) & 1u);
    return (u16)(r >> 16);
}
__device__ __forceinline__ u32 enc_max(float f){ u32 b = __builtin_bit_cast(u32, f); return (b & 0x80000000u) ? ~b : (b | 0x80000000u); }
__device__ __forceinline__ float dec_max(u32 u){ u32 b = (u & 0x80000000u) ? (u & 0x7fffffffu) : ~u; return __builtin_bit_cast(float, b); }

// ---------------------------------------------------------------------------
// Per-input dtype detection, all 10 inputs in one launch. flag 1=bf16, 0=fp32.
// ---------------------------------------------------------------------------
struct DetectArgs { const u32* p[10]; int nw[10]; };

__global__ void detect_all(DetectArgs a, u32* __restrict__ flags)
{
    __shared__ int cnt[256];
    int k = blockIdx.x;
    const u32* src = a.p[k];
    int nwords = a.nw[k];
    int t = threadIdx.x; int c = 0;
    for (int i = t; i < nwords; i += 256) {
        u32 w = src[i];
        int ea = (int)((w >> 7)  & 0xFF);
        int eb = (int)((w >> 23) & 0xFF);
        c += (ea >= 112 && ea <= 143) ? 1 : 0;
        c += (eb >= 112 && eb <= 143) ? 1 : 0;
    }
    cnt[t] = c; __syncthreads();
    for (int s = 128; s; s >>= 1) { if (t < s) cnt[t] += cnt[t + s]; __syncthreads(); }
    if (t == 0) flags[k] = (cnt[0] >= (nwords * 3) / 2) ? 1u : 0u;  // 75% of 2*nwords
}

// ---------------------------------------------------------------------------
// Convert n elements (n % 8 == 0) from src (fp32 or bf16 per its flag) to bf16.
// ---------------------------------------------------------------------------
__global__ __launch_bounds__(256)
void conv_kernel(const void* __restrict__ src, u16* __restrict__ dst, int n,
                 const u32* __restrict__ gflag)
{
    int i = (blockIdx.x * 256 + threadIdx.x) * 8;
    if (i >= n) return;
    if (*gflag) {
        *(uint4*)(dst + i) = *(const uint4*)((const u16*)src + i);
    } else {
        const float* s = (const float*)src + i;
        u16 tmp[8];
        #pragma unroll
        for (int j = 0; j < 8; ++j) tmp[j] = f2b(s[j]);
        *(uint4*)(dst + i) = *(uint4*)tmp;
    }
}

// ---------------------------------------------------------------------------
// GEMM (reference-literal): C[r][c] = sum_k A[r][k] * W[c][k] + bias[c]
// (x @ W.T, W stored [out][in]). 128x128 tile, 4 waves, 16x16x32 bf16 MFMA.
// OUT_BF16: 0 -> fp32 C, 1 -> bf16 C.
// ---------------------------------------------------------------------------
template<int OUT_BF16>
__global__ __launch_bounds__(256)
void gemm_nt(const u16* __restrict__ A, const u16* __restrict__ Bm,
             const u16* __restrict__ bias, void* __restrict__ C)
{
    const int K = DM, Nc = DM;
    __shared__ u16 As[128][40];
    __shared__ u16 Bs[128][40];
    int t = threadIdx.x;
    int wave = t >> 6, lane = t & 63;
    int wm = wave >> 1, wn = wave & 1;
    int quad = lane >> 4, l16 = lane & 15;
    int bm = blockIdx.x * 128, bn = blockIdx.y * 128;
    f32x4 acc[4][4];
    #pragma unroll
    for (int i = 0; i < 4; ++i)
        #pragma unroll
        for (int j = 0; j < 4; ++j) acc[i][j] = (f32x4){0.f,0.f,0.f,0.f};

    for (int k0 = 0; k0 < K; k0 += 32) {
        #pragma unroll
        for (int it = 0; it < 2; ++it) {
            int L = t + it * 256;
            int r = L >> 2, c = (L & 3) * 8;
            *(uint4*)&As[r][c] = *(const uint4*)(A + (size_t)(bm + r) * K + k0 + c);
            *(uint4*)&Bs[r][c] = *(const uint4*)(Bm + (size_t)(bn + r) * K + k0 + c);
        }
        __syncthreads();
        bf16x8 af[4], bfr[4];
        #pragma unroll
        for (int i = 0; i < 4; ++i) {
            af[i]  = *(const bf16x8*)&As[wm*64 + i*16 + l16][quad*8];
            bfr[i] = *(const bf16x8*)&Bs[wn*64 + i*16 + l16][quad*8];
        }
        #pragma unroll
        for (int i = 0; i < 4; ++i)
            #pragma unroll
            for (int j = 0; j < 4; ++j)
                acc[i][j] = __builtin_amdgcn_mfma_f32_16x16x32_bf16(af[i], bfr[j], acc[i][j], 0, 0, 0);
        __syncthreads();
    }
    #pragma unroll
    for (int i = 0; i < 4; ++i) {
        #pragma unroll
        for (int j = 0; j < 4; ++j) {
            int col = bn + wn*64 + j*16 + l16;
            float bv = b2f(bias[col]);
            #pragma unroll
            for (int r = 0; r < 4; ++r) {
                int row = bm + wm*64 + i*16 + quad*4 + r;
                float v = acc[i][j][r] + bv;
                if (OUT_BF16) ((u16*)C)[(size_t)row * Nc + col] = f2b(v);
                else          ((float*)C)[(size_t)row * Nc + col] = v;
            }
        }
    }
}

// ---------------------------------------------------------------------------
// prep2: projC[272][64]: bf16(proj[m][d]) for m<266, zeros for pad rows.
// Also zero gpart/gmax.
// ---------------------------------------------------------------------------
__global__ __launch_bounds__(256)
void prep2(const void* __restrict__ proj, u16* __restrict__ projC,
           u32* __restrict__ gpart, u32* __restrict__ gmax,
           const u32* __restrict__ gflag)
{
    int i = blockIdx.x * 256 + threadIdx.x;
    if (i < 256) gpart[i] = 0u;
    if (i == 256) *gmax = 0u;
    if (i < MP * DH) {
        u16 v = 0;
        if (i < MF * DH)
            v = (*gflag) ? ((const u16*)proj)[i] : f2b(((const float*)proj)[i]);
        projC[i] = v;
    }
}

// ---------------------------------------------------------------------------
// MFMA feature map. Block = 64 rows of one (b,h); 4 waves x 16 rows.
// data_dash[64][272] = dn[64][64] @ projP^T via 16x16x32 bf16 MFMA with
// hi/lo split of fp32 dn (keeps fp32-grade A precision).
// MODE 0: Q (per-row stab, write). MODE 1: K global-max only. MODE 2: K write.
// LDS: proj staged XOR-swizzled (phase 1), reused as output stage (phase 2).
// ---------------------------------------------------------------------------
template<int MODE>
__global__ __launch_bounds__(256)
void feat_mfma(const float* __restrict__ X, const u16* __restrict__ projP,
               u16* __restrict__ OutP, u32* __restrict__ gpart,
               const u32* __restrict__ gmax)
{
    int blk = blockIdx.x;             // 0..2047
    int bh = blk >> 6, nt = blk & 63;
    int b = bh >> 4, h = bh & 15;
    int n0 = nt * 64;
    int t = threadIdx.x;
    int lane = t & 63, w = t >> 6;
    int quad = lane >> 4, l16 = lane & 15;

    __shared__ uint4 smemU[2240];     // 35840 B: projS (34816) then outS[64][280]
    u16* smem16 = (u16*)smemU;

    // A rows (issue global loads early): row = n0 + w*16 + l16, k = ks*32+quad*8+i
    const float* xrow = X + ((size_t)(b * NSEQ + n0 + w*16 + l16)) * DM + h * DH;
    float va[2][8];
    #pragma unroll
    for (int ks = 0; ks < 2; ++ks) {
        float4 u0 = *(const float4*)(xrow + ks*32 + quad*8);
        float4 u1 = *(const float4*)(xrow + ks*32 + quad*8 + 4);
        va[ks][0]=u0.x; va[ks][1]=u0.y; va[ks][2]=u0.z; va[ks][3]=u0.w;
        va[ks][4]=u1.x; va[ks][5]=u1.y; va[ks][6]=u1.z; va[ks][7]=u1.w;
    }

    // stage proj into LDS, XOR-swizzled: row m at byte m*128, byte^((m&7)<<4)
    for (int i = t; i < 2176; i += 256) {
        int m = i >> 3, c = i & 7;
        uint4 v = *(const uint4*)(projP + m*64 + c*8);
        int dstb = m*128 + ((c*16) ^ ((m & 7) << 4));
        *(uint4*)((char*)smemU + dstb) = v;
    }

    // hi/lo bf16 split + diag (sum of squares over this lane's 16 k's)
    bf16x8 ahi[2], alo[2];
    float sq = 0.f;
    #pragma unroll
    for (int ks = 0; ks < 2; ++ks) {
        #pragma unroll
        for (int i = 0; i < 8; ++i) {
            float v = va[ks][i] * DNORM;
            sq += v * v;
            u16 hb = f2b(v);
            float hv = b2f(hb);
            ahi[ks][i] = __builtin_bit_cast(__bf16, hb);
            alo[ks][i] = __builtin_bit_cast(__bf16, f2b(v - hv));
        }
    }
    sq += __shfl_xor(sq, 16, 64);
    sq += __shfl_xor(sq, 32, 64);
    float diag_my = 0.5f * sq;        // diag for row (w*16 + l16)

    __syncthreads();                  // projS ready

    f32x4 acc[17];
    #pragma unroll
    for (int j = 0; j < 17; ++j) acc[j] = (f32x4){0.f,0.f,0.f,0.f};
    #pragma unroll
    for (int j = 0; j < 17; ++j) {
        int m = j*16 + l16;
        #pragma unroll
        for (int ks = 0; ks < 2; ++ks) {
            int off = m*128 + (((quad*16) + ks*64) ^ ((m & 7) << 4));
            bf16x8 bf = *(const bf16x8*)((const char*)smemU + off);
            acc[j] = __builtin_amdgcn_mfma_f32_16x16x32_bf16(ahi[ks], bf, acc[j], 0, 0, 0);
            acc[j] = __builtin_amdgcn_mfma_f32_16x16x32_bf16(alo[ks], bf, acc[j], 0, 0, 0);
        }
    }
    // lane holds rows quad*4+r, cols m=j*16+l16

    // per-row max over valid m (m<266): tiles 0..15 all valid; tile 16: l16<10
    float rmax[4];
    #pragma unroll
    for (int r = 0; r < 4; ++r) rmax[r] = -3.4e38f;
    #pragma unroll
    for (int j = 0; j < 16; ++j)
        #pragma unroll
        for (int r = 0; r < 4; ++r) rmax[r] = fmaxf(rmax[r], acc[j][r]);
    if (l16 < MF - 256) {
        #pragma unroll
        for (int r = 0; r < 4; ++r) rmax[r] = fmaxf(rmax[r], acc[16][r]);
    }
    #pragma unroll
    for (int s = 1; s < 16; s <<= 1)
        #pragma unroll
        for (int r = 0; r < 4; ++r)
            rmax[r] = fmaxf(rmax[r], __shfl_xor(rmax[r], s, 64));

    if (MODE == 1) {
        float wm2 = fmaxf(fmaxf(rmax[0], rmax[1]), fmaxf(rmax[2], rmax[3]));
        wm2 = fmaxf(wm2, __shfl_xor(wm2, 16, 64));
        wm2 = fmaxf(wm2, __shfl_xor(wm2, 32, 64));
        if (lane == 0) atomicMax(&gpart[blk & 255], enc_max(wm2));
        return;
    }

    float gstab = (MODE == 2) ? dec_max(*gmax) : 0.f;
    float dg[4];
    #pragma unroll
    for (int r = 0; r < 4; ++r) dg[r] = __shfl(diag_my, quad*4 + r, 64);

    __syncthreads();                  // all proj reads done; reuse LDS as outS

    #pragma unroll
    for (int j = 0; j < 17; ++j) {
        int m = j*16 + l16;
        #pragma unroll
        for (int r = 0; r < 4; ++r) {
            float stab = (MODE == 0) ? rmax[r] : gstab;
            float val = RATIO * (__expf(acc[j][r] - dg[r] - stab) + KEPS);
            u16 ov = (m < MF) ? f2b(val) : (u16)0;
            smem16[(w*16 + quad*4 + r) * 280 + m] = ov;  // 280-pad: bank spread
        }
    }
    __syncthreads();

    // coalesced store: 64 rows x 272 u16 (= 34 uint4 chunks per row)
    u16* obase = OutP + ((size_t)bh * NSEQ + n0) * MP;
    for (int i = t; i < 2176; i += 256) {
        int row = i / 34, c = i - row * 34;
        *(uint4*)(obase + row*MP + c*8) = *(const uint4*)(smem16 + row*280 + c*8);
    }
}

__global__ void gmax_reduce(const u32* __restrict__ gpart, u32* __restrict__ gmax)
{
    __shared__ u32 r[256];
    int t = threadIdx.x;
    r[t] = gpart[t]; __syncthreads();
    for (int s = 128; s; s >>= 1) { if (t < s) r[t] = max(r[t], r[t + s]); __syncthreads(); }
    if (t == 0) *gmax = r[0];
}

// ---------------------------------------------------------------------------
// Chunk-parallel causal scan (3 phases).
// Lane layout: block = 4 waves; wave w owns d in [w*16, w*16+16); lane =
// (mg, dl): mg = quad owns features m in [mg*68, mg*68+68), dl -> d = w*16+dl.
// Feature-reduction is intra-wave (shfl_xor 16/32) -> no reduce barrier.
// ---------------------------------------------------------------------------

// Phase A: per-chunk local sums S_c[m][d] = sum_{n in chunk} k'[m]*v[d],
//          z_c[m] = sum k'[m].  grid = B*H*NC = 512.
__global__ __launch_bounds__(256)
void chunk_sums(const u16* __restrict__ Kp, const u16* __restrict__ Vb,
                float* __restrict__ Sloc, float* __restrict__ zloc)
{
    int bhc = blockIdx.x;
    int bh = bhc >> 4, c = bhc & (NC - 1);
    int b = bh >> 4, h = bh & 15;
    int t = threadIdx.x;
    int w = t >> 6, mg = (t >> 4) & 3, dl = t & 15;
    int d = w * 16 + dl, m0 = mg * 68, base = mg * 34;

    __shared__ u32 sb[2][168];   // k (136 dwords) + v (32 dwords)

    float ctx[68], zl[68];
    #pragma unroll
    for (int j = 0; j < 68; ++j) { ctx[j] = 0.f; zl[j] = 0.f; }

    int n0 = c * CH;
    const u32* kr = (const u32*)(Kp + ((size_t)bh * NSEQ + n0) * MP);
    const u32* vr = (const u32*)(Vb + ((size_t)(b * NSEQ + n0)) * DM + h * DH);

    {   // prologue stage token 0
        if (t < 136)      sb[0][t] = kr[t];
        else if (t < 168) sb[0][t] = vr[t - 136];
    }
    __syncthreads();

    for (int ni = 0; ni < CH; ++ni) {
        int cur = ni & 1;
        u32 pf = 0;
        if (ni < CH - 1) {   // issue next-token loads early
            const u32* kn = kr + (size_t)(ni + 1) * 136;
            const u32* vn = vr + (size_t)(ni + 1) * 512;
            if (t < 136)      pf = kn[t];
            else if (t < 168) pf = vn[t - 136];
        }
        const u32* kb = sb[cur];
        float vv = b2f(((const u16*)(sb[cur] + 136))[d]);
        #pragma unroll
        for (int j = 0; j < 34; ++j) {
            u32 kw = kb[base + j];
            float k0 = b2f_lo(kw), k1 = b2f_hi(kw);
            int j2 = j * 2;
            ctx[j2]     += k0 * vv;  zl[j2]     += k0;
            ctx[j2 + 1] += k1 * vv;  zl[j2 + 1] += k1;
        }
        if (ni < CH - 1 && t < 168) sb[cur ^ 1][t] = pf;
        __syncthreads();
    }

    size_t sbase = (size_t)bhc * MD;
    #pragma unroll
    for (int j = 0; j < 68; ++j)
        Sloc[sbase + (size_t)(m0 + j) * 64 + d] = ctx[j];
    if (w == 0 && dl == 0) {
        #pragma unroll
        for (int j = 0; j < 68; ++j)
            zloc[(size_t)bhc * MP + m0 + j] = zl[j];
    }
}

// Phase B: in-place exclusive prefix over chunks, per (b,h).
// grid = (32*MD)/256 = 2176 blocks exactly.
__global__ __launch_bounds__(256)
void chunk_prefix(float* __restrict__ Sloc, float* __restrict__ zloc)
{
    int gid = blockIdx.x * 256 + threadIdx.x;
    {
        int bh = gid / MD, e = gid - bh * MD;
        float run = 0.f;
        #pragma unroll
        for (int c = 0; c < NC; ++c) {
            size_t o = ((size_t)(bh * NC + c)) * MD + e;
            float v = Sloc[o]; Sloc[o] = run; run += v;
        }
    }
    if (gid < B_ * H_ * MP) {
        int bh = gid / MP, m = gid - bh * MP;
        float run = 0.f;
        #pragma unroll
        for (int c = 0; c < NC; ++c) {
            size_t o = ((size_t)(bh * NC + c)) * MP + m;
            float v = zloc[o]; zloc[o] = run; run += v;
        }
    }
}

// Phase C: rescan each chunk from its carry. grid = 512.
__global__ __launch_bounds__(256)
void scan_chunk(const u16* __restrict__ Qp, const u16* __restrict__ Kp,
                const u16* __restrict__ Vb, const float* __restrict__ Scar,
                const float* __restrict__ zcar, u16* __restrict__ attn)
{
    int bhc = blockIdx.x;
    int bh = bhc >> 4, c = bhc & (NC - 1);
    int b = bh >> 4, h = bh & 15;
    int t = threadIdx.x;
    int w = t >> 6, mg = (t >> 4) & 3, dl = t & 15;
    int d = w * 16 + dl, m0 = mg * 68, base = mg * 34;

    __shared__ u32 sb[2][304];   // q (136) + k (136) + v (32) dwords

    float ctx[68], zl[68];
    size_t sbase = (size_t)bhc * MD;
    #pragma unroll
    for (int j = 0; j < 68; ++j)
        ctx[j] = Scar[sbase + (size_t)(m0 + j) * 64 + d];
    #pragma unroll
    for (int j = 0; j < 68; ++j)
        zl[j] = zcar[(size_t)bhc * MP + m0 + j];

    int n0 = c * CH;
    const u32* qr = (const u32*)(Qp + ((size_t)bh * NSEQ + n0) * MP);
    const u32* kr = (const u32*)(Kp + ((size_t)bh * NSEQ + n0) * MP);
    const u32* vr = (const u32*)(Vb + ((size_t)(b * NSEQ + n0)) * DM + h * DH);
    u16* arow = attn + ((size_t)(b * NSEQ + n0)) * DM + h * DH + d;

    {
        sb[0][t] = (t < 136) ? qr[t] : kr[t - 136];
        if (t < 48) sb[0][t + 256] = (t < 16) ? kr[t + 120] : vr[t - 16];
    }
    __syncthreads();

    for (int ni = 0; ni < CH; ++ni) {
        int cur = ni & 1;
        u32 pf0 = 0, pf1 = 0;
        if (ni < CH - 1) {   // issue next-token loads early
            const u32* qn = qr + (size_t)(ni + 1) * 136;
            const u32* kn = kr + (size_t)(ni + 1) * 136;
            const u32* vn = vr + (size_t)(ni + 1) * 512;
            pf0 = (t < 136) ? qn[t] : kn[t - 136];
            if (t < 48) pf1 = (t < 16) ? kn[t + 120] : vn[t - 16];
        }

        const u32* qb = sb[cur];
        const u32* kb = sb[cur] + 136;
        float vv = b2f(((const u16*)(sb[cur] + 272))[d]);
        float np0 = 0.f, np1 = 0.f, dp0 = 0.f, dp1 = 0.f, sq0 = 0.f, sq1 = 0.f;
        #pragma unroll
        for (int j = 0; j < 34; ++j) {
            u32 kw = kb[base + j], qw = qb[base + j];
            float k0 = b2f_lo(kw), k1 = b2f_hi(kw);
            float q0 = b2f_lo(qw), q1 = b2f_hi(qw);
            int j2 = j * 2;
            ctx[j2]     += k0 * vv;  zl[j2]     += k0;
            np0 += q0 * ctx[j2];     dp0 += q0 * zl[j2];     sq0 += q0;
            ctx[j2 + 1] += k1 * vv;  zl[j2 + 1] += k1;
            np1 += q1 * ctx[j2 + 1]; dp1 += q1 * zl[j2 + 1]; sq1 += q1;
        }
        float num = np0 + np1;
        float den = dp0 + dp1 + CEPS * (sq0 + sq1);
        num += __shfl_xor(num, 16, 64);
        den += __shfl_xor(den, 16, 64);
        num += __shfl_xor(num, 32, 64);
        den += __shfl_xor(den, 32, 64);

        if (ni < CH - 1) {
            sb[cur ^ 1][t] = pf0;
            if (t < 48) sb[cur ^ 1][t + 256] = pf1;
        }
        if (mg == 0) arow[(size_t)ni * DM] = f2b(num / den);
        __syncthreads();
    }
}

// ---------------------------------------------------------------------------
extern "C" void kernel_launch(void* const* d_in, const int* in_sizes, int n_in,
                              void* d_out, int out_size, void* d_ws, size_t ws_size,
                              hipStream_t stream)
{
    (void)n_in; (void)out_size; (void)ws_size;
    // dict order: x, Wq, bq, Wk, bk, Wv, bv, Wo, bo, proj (sizes verified r4/r5)
    const void* x  = d_in[0];
    const void* Wq = d_in[1]; const void* bq = d_in[2];
    const void* Wk = d_in[3]; const void* bk = d_in[4];
    const void* Wv = d_in[5]; const void* bv = d_in[6];
    const void* Wo = d_in[7]; const void* bo = d_in[8];
    const void* proj = d_in[9];

    char* ws = (char*)d_ws;
    size_t off = 0;
    auto alloc = [&](size_t bytes) -> char* {
        char* p = ws + off; off += (bytes + 255) & ~(size_t)255; return p;
    };
    float* QKf  = (float*)alloc((size_t)NROWS * DM * 4);
    u16*   Vb   = (u16*)alloc((size_t)NROWS * DM * 2);
    u16*   Qp   = (u16*)alloc((size_t)NHROWS * MP * 2);
    u16*   Kp   = (u16*)alloc((size_t)NHROWS * MP * 2);
    u16*   projC= (u16*)alloc((size_t)MP * DH * 2);   // padded [272][64]
    u16*   Wb   = (u16*)alloc((size_t)DM * DM * 2);
    u16*   bqb  = (u16*)alloc(DM * 2);
    u16*   bkb  = (u16*)alloc(DM * 2);
    u16*   bvb  = (u16*)alloc(DM * 2);
    u16*   bob  = (u16*)alloc(DM * 2);
    u32*   flags= (u32*)alloc(16 * 4);
    u32*   gmax = (u32*)alloc(256);
    u32*   gpart= (u32*)alloc(256 * 4);
    char*  xatt = alloc((size_t)NROWS * DM * 2);
    u16*   xb   = (u16*)xatt;    // alias: xb dead after gemm K
    u16*   attn = (u16*)xatt;    // scan writes afterwards
    // chunk-scan carry state (35.7 MB + 0.6 MB)
    float* Sloc = (float*)alloc((size_t)(B_ * H_ * NC) * MD * 4);
    float* zloc = (float*)alloc((size_t)(B_ * H_ * NC) * MP * 4);

    const int nW = DM * DM, nX = NROWS * DM;
    dim3 gg(NROWS / 128, DM / 128);

    DetectArgs da;
    for (int i = 0; i < 10; ++i) {
        int n = in_sizes[i];
        int nwords = n / 2; if (nwords > 4096) nwords = 4096;
        da.p[i] = (const u32*)d_in[i];
        da.nw[i] = nwords;
    }
    detect_all<<<10, 256, 0, stream>>>(da, flags);

    prep2<<<(MP * DH + 255) / 256, 256, 0, stream>>>(proj, projC, gpart, gmax, flags + 9);
    conv_kernel<<<(nX + 2047) / 2048, 256, 0, stream>>>(x, xb, nX, flags + 0);
    conv_kernel<<<1, 256, 0, stream>>>(bq, bqb, DM, flags + 2);
    conv_kernel<<<1, 256, 0, stream>>>(bk, bkb, DM, flags + 4);
    conv_kernel<<<1, 256, 0, stream>>>(bv, bvb, DM, flags + 6);
    conv_kernel<<<1, 256, 0, stream>>>(bo, bob, DM, flags + 8);

    conv_kernel<<<(nW + 2047) / 2048, 256, 0, stream>>>(Wv, Wb, nW, flags + 5);
    gemm_nt<1><<<gg, 256, 0, stream>>>(xb, Wb, bvb, Vb);

    conv_kernel<<<(nW + 2047) / 2048, 256, 0, stream>>>(Wq, Wb, nW, flags + 1);
    gemm_nt<0><<<gg, 256, 0, stream>>>(xb, Wb, bqb, QKf);
    feat_mfma<0><<<NHROWS / 64, 256, 0, stream>>>(QKf, projC, Qp, gpart, gmax);

    conv_kernel<<<(nW + 2047) / 2048, 256, 0, stream>>>(Wk, Wb, nW, flags + 3);
    gemm_nt<0><<<gg, 256, 0, stream>>>(xb, Wb, bkb, QKf);
    feat_mfma<1><<<NHROWS / 64, 256, 0, stream>>>(QKf, projC, Kp, gpart, gmax);
    gmax_reduce<<<1, 256, 0, stream>>>(gpart, gmax);
    feat_mfma<2><<<NHROWS / 64, 256, 0, stream>>>(QKf, projC, Kp, gpart, gmax);

    // chunk-parallel causal scan: local sums -> exclusive prefix -> rescan
    chunk_sums<<<B_ * H_ * NC, 256, 0, stream>>>(Kp, Vb, Sloc, zloc);
    chunk_prefix<<<(B_ * H_ * MD) / 256, 256, 0, stream>>>(Sloc, zloc);
    scan_chunk<<<B_ * H_ * NC, 256, 0, stream>>>(Qp, Kp, Vb, Sloc, zloc, attn);

    conv_kernel<<<(nW + 2047) / 2048, 256, 0, stream>>>(Wo, Wb, nW, flags + 7);
    // OUTPUT IS FP32 (reference's output dtype, per harness instructions).
    gemm_nt<0><<<gg, 256, 0, stream>>>(attn, Wb, bob, d_out);
}

// Round 4
// 473.826 us; speedup vs baseline: 29.7386x; 2.0506x over previous
//
#include <hip/hip_runtime.h>

#define B_    2
#define NSEQ  4096
#define DM    1024
#define H_    16
#define DH    64
#define MF    266
#define MP    288          // padded feature count, 9 x 32 (pads are zero)
#define NROWS (B_*NSEQ)    // 8192
#define NHROWS (B_*H_*NSEQ) // 131072
#define RATIO 0.06131393394849658f   // 266^-0.5
#define DNORM 0.3535533905932738f    // 64^-0.25
#define KEPS  1e-4f
#define CEPS  1e-6f

// chunked causal scan geometry
#define CH    128                 // tokens per chunk
#define NC    32                  // chunks per (b,h) = NSEQ/CH
#define SROW  (65*MP)             // per-chunk state: 64 S^T rows + 1 z row = 18720

typedef unsigned short u16;
typedef unsigned int   u32;

typedef __bf16 bf16x8 __attribute__((ext_vector_type(8)));
typedef float  f32x4  __attribute__((ext_vector_type(4)));

__device__ __forceinline__ float b2f(u16 u){ u32 x = ((u32)u) << 16; return __builtin_bit_cast(float, x); }
__device__ __forceinline__ u16 f2b(float f){
    u32 x = __builtin_bit_cast(u32, f);
    u32 r = x + 0x7fffu + ((x >> 16) & 1u);
    return (u16)(r >> 16);
}
__device__ __forceinline__ u32 enc_max(float f){ u32 b = __builtin_bit_cast(u32, f); return (b & 0x80000000u) ? ~b : (b | 0x80000000u); }
__device__ __forceinline__ float dec_max(u32 u){ u32 b = (u & 0x80000000u) ? (u & 0x7fffffffu) : ~u; return __builtin_bit_cast(float, b); }

// ---------------------------------------------------------------------------
// Per-input dtype detection, all 10 inputs in one launch. flag 1=bf16, 0=fp32.
// ---------------------------------------------------------------------------
struct DetectArgs { const u32* p[10]; int nw[10]; };

__global__ void detect_all(DetectArgs a, u32* __restrict__ flags)
{
    __shared__ int cnt[256];
    int k = blockIdx.x;
    const u32* src = a.p[k];
    int nwords = a.nw[k];
    int t = threadIdx.x; int c = 0;
    for (int i = t; i < nwords; i += 256) {
        u32 w = src[i];
        int ea = (int)((w >> 7)  & 0xFF);
        int eb = (int)((w >> 23) & 0xFF);
        c += (ea >= 112 && ea <= 143) ? 1 : 0;
        c += (eb >= 112 && eb <= 143) ? 1 : 0;
    }
    cnt[t] = c; __syncthreads();
    for (int s = 128; s; s >>= 1) { if (t < s) cnt[t] += cnt[t + s]; __syncthreads(); }
    if (t == 0) flags[k] = (cnt[0] >= (nwords * 3) / 2) ? 1u : 0u;  // 75% of 2*nwords
}

// ---------------------------------------------------------------------------
// Convert n elements (n % 8 == 0) from src (fp32 or bf16 per its flag) to bf16.
// ---------------------------------------------------------------------------
__global__ __launch_bounds__(256)
void conv_kernel(const void* __restrict__ src, u16* __restrict__ dst, int n,
                 const u32* __restrict__ gflag)
{
    int i = (blockIdx.x * 256 + threadIdx.x) * 8;
    if (i >= n) return;
    if (*gflag) {
        *(uint4*)(dst + i) = *(const uint4*)((const u16*)src + i);
    } else {
        const float* s = (const float*)src + i;
        u16 tmp[8];
        #pragma unroll
        for (int j = 0; j < 8; ++j) tmp[j] = f2b(s[j]);
        *(uint4*)(dst + i) = *(uint4*)tmp;
    }
}

// ---------------------------------------------------------------------------
// GEMM (reference-literal): C[r][c] = sum_k A[r][k] * W[c][k] + bias[c]
// ---------------------------------------------------------------------------
template<int OUT_BF16>
__global__ __launch_bounds__(256)
void gemm_nt(const u16* __restrict__ A, const u16* __restrict__ Bm,
             const u16* __restrict__ bias, void* __restrict__ C)
{
    const int K = DM, Nc = DM;
    __shared__ u16 As[128][40];
    __shared__ u16 Bs[128][40];
    int t = threadIdx.x;
    int wave = t >> 6, lane = t & 63;
    int wm = wave >> 1, wn = wave & 1;
    int quad = lane >> 4, l16 = lane & 15;
    int bm = blockIdx.x * 128, bn = blockIdx.y * 128;
    f32x4 acc[4][4];
    #pragma unroll
    for (int i = 0; i < 4; ++i)
        #pragma unroll
        for (int j = 0; j < 4; ++j) acc[i][j] = (f32x4){0.f,0.f,0.f,0.f};

    for (int k0 = 0; k0 < K; k0 += 32) {
        #pragma unroll
        for (int it = 0; it < 2; ++it) {
            int L = t + it * 256;
            int r = L >> 2, c = (L & 3) * 8;
            *(uint4*)&As[r][c] = *(const uint4*)(A + (size_t)(bm + r) * K + k0 + c);
            *(uint4*)&Bs[r][c] = *(const uint4*)(Bm + (size_t)(bn + r) * K + k0 + c);
        }
        __syncthreads();
        bf16x8 af[4], bfr[4];
        #pragma unroll
        for (int i = 0; i < 4; ++i) {
            af[i]  = *(const bf16x8*)&As[wm*64 + i*16 + l16][quad*8];
            bfr[i] = *(const bf16x8*)&Bs[wn*64 + i*16 + l16][quad*8];
        }
        #pragma unroll
        for (int i = 0; i < 4; ++i)
            #pragma unroll
            for (int j = 0; j < 4; ++j)
                acc[i][j] = __builtin_amdgcn_mfma_f32_16x16x32_bf16(af[i], bfr[j], acc[i][j], 0, 0, 0);
        __syncthreads();
    }
    #pragma unroll
    for (int i = 0; i < 4; ++i) {
        #pragma unroll
        for (int j = 0; j < 4; ++j) {
            int col = bn + wn*64 + j*16 + l16;
            float bv = b2f(bias[col]);
            #pragma unroll
            for (int r = 0; r < 4; ++r) {
                int row = bm + wm*64 + i*16 + quad*4 + r;
                float v = acc[i][j][r] + bv;
                if (OUT_BF16) ((u16*)C)[(size_t)row * Nc + col] = f2b(v);
                else          ((float*)C)[(size_t)row * Nc + col] = v;
            }
        }
    }
}

// ---------------------------------------------------------------------------
// prep2: projC[288][64]: bf16(proj[m][d]) for m<266, zeros for pad rows.
// ---------------------------------------------------------------------------
__global__ __launch_bounds__(256)
void prep2(const void* __restrict__ proj, u16* __restrict__ projC,
           u32* __restrict__ gpart, u32* __restrict__ gmax,
           const u32* __restrict__ gflag)
{
    int i = blockIdx.x * 256 + threadIdx.x;
    if (i < 256) gpart[i] = 0u;
    if (i == 256) *gmax = 0u;
    if (i < MP * DH) {
        u16 v = 0;
        if (i < MF * DH)
            v = (*gflag) ? ((const u16*)proj)[i] : f2b(((const float*)proj)[i]);
        projC[i] = v;
    }
}

// ---------------------------------------------------------------------------
// MFMA feature map. Block = 64 rows of one (b,h); 4 waves x 16 rows.
// ---------------------------------------------------------------------------
template<int MODE>
__global__ __launch_bounds__(256)
void feat_mfma(const float* __restrict__ X, const u16* __restrict__ projP,
               u16* __restrict__ OutP, u32* __restrict__ gpart,
               const u32* __restrict__ gmax)
{
    int blk = blockIdx.x;             // 0..2047
    int bh = blk >> 6, nt = blk & 63;
    int b = bh >> 4, h = bh & 15;
    int n0 = nt * 64;
    int t = threadIdx.x;
    int lane = t & 63, w = t >> 6;
    int quad = lane >> 4, l16 = lane & 15;

    __shared__ uint4 smemU[2368];     // max(proj 288*128B, out 64*296*2B) = 37888B
    u16* smem16 = (u16*)smemU;

    const float* xrow = X + ((size_t)(b * NSEQ + n0 + w*16 + l16)) * DM + h * DH;
    float va[2][8];
    #pragma unroll
    for (int ks = 0; ks < 2; ++ks) {
        float4 u0 = *(const float4*)(xrow + ks*32 + quad*8);
        float4 u1 = *(const float4*)(xrow + ks*32 + quad*8 + 4);
        va[ks][0]=u0.x; va[ks][1]=u0.y; va[ks][2]=u0.z; va[ks][3]=u0.w;
        va[ks][4]=u1.x; va[ks][5]=u1.y; va[ks][6]=u1.z; va[ks][7]=u1.w;
    }

    // stage proj into LDS, XOR-swizzled: row m at byte m*128, byte^((m&7)<<4)
    for (int i = t; i < 2304; i += 256) {
        int m = i >> 3, c = i & 7;
        uint4 v = *(const uint4*)(projP + m*64 + c*8);
        int dstb = m*128 + ((c*16) ^ ((m & 7) << 4));
        *(uint4*)((char*)smemU + dstb) = v;
    }

    bf16x8 ahi[2], alo[2];
    float sq = 0.f;
    #pragma unroll
    for (int ks = 0; ks < 2; ++ks) {
        #pragma unroll
        for (int i = 0; i < 8; ++i) {
            float v = va[ks][i] * DNORM;
            sq += v * v;
            u16 hb = f2b(v);
            float hv = b2f(hb);
            ahi[ks][i] = __builtin_bit_cast(__bf16, hb);
            alo[ks][i] = __builtin_bit_cast(__bf16, f2b(v - hv));
        }
    }
    sq += __shfl_xor(sq, 16, 64);
    sq += __shfl_xor(sq, 32, 64);
    float diag_my = 0.5f * sq;

    __syncthreads();                  // projS ready

    f32x4 acc[18];
    #pragma unroll
    for (int j = 0; j < 18; ++j) acc[j] = (f32x4){0.f,0.f,0.f,0.f};
    #pragma unroll
    for (int j = 0; j < 18; ++j) {
        int m = j*16 + l16;
        #pragma unroll
        for (int ks = 0; ks < 2; ++ks) {
            int off = m*128 + (((quad*16) + ks*64) ^ ((m & 7) << 4));
            bf16x8 bf = *(const bf16x8*)((const char*)smemU + off);
            acc[j] = __builtin_amdgcn_mfma_f32_16x16x32_bf16(ahi[ks], bf, acc[j], 0, 0, 0);
            acc[j] = __builtin_amdgcn_mfma_f32_16x16x32_bf16(alo[ks], bf, acc[j], 0, 0, 0);
        }
    }

    // per-row max over valid m: tiles 0..15 full; tile 16: l16<10; tile 17: pad
    float rmax[4];
    #pragma unroll
    for (int r = 0; r < 4; ++r) rmax[r] = -3.4e38f;
    #pragma unroll
    for (int j = 0; j < 16; ++j)
        #pragma unroll
        for (int r = 0; r < 4; ++r) rmax[r] = fmaxf(rmax[r], acc[j][r]);
    if (l16 < MF - 256) {
        #pragma unroll
        for (int r = 0; r < 4; ++r) rmax[r] = fmaxf(rmax[r], acc[16][r]);
    }
    #pragma unroll
    for (int s = 1; s < 16; s <<= 1)
        #pragma unroll
        for (int r = 0; r < 4; ++r)
            rmax[r] = fmaxf(rmax[r], __shfl_xor(rmax[r], s, 64));

    if (MODE == 1) {
        float wm2 = fmaxf(fmaxf(rmax[0], rmax[1]), fmaxf(rmax[2], rmax[3]));
        wm2 = fmaxf(wm2, __shfl_xor(wm2, 16, 64));
        wm2 = fmaxf(wm2, __shfl_xor(wm2, 32, 64));
        if (lane == 0) atomicMax(&gpart[blk & 255], enc_max(wm2));
        return;
    }

    float gstab = (MODE == 2) ? dec_max(*gmax) : 0.f;
    float dg[4];
    #pragma unroll
    for (int r = 0; r < 4; ++r) dg[r] = __shfl(diag_my, quad*4 + r, 64);

    __syncthreads();                  // all proj reads done; reuse LDS as outS

    #pragma unroll
    for (int j = 0; j < 18; ++j) {
        int m = j*16 + l16;
        #pragma unroll
        for (int r = 0; r < 4; ++r) {
            float stab = (MODE == 0) ? rmax[r] : gstab;
            float val = RATIO * (__expf(acc[j][r] - dg[r] - stab) + KEPS);
            u16 ov = (m < MF) ? f2b(val) : (u16)0;
            smem16[(w*16 + quad*4 + r) * 296 + m] = ov;
        }
    }
    __syncthreads();

    // coalesced store: 64 rows x 288 u16 (= 36 uint4 chunks per row)
    u16* obase = OutP + ((size_t)bh * NSEQ + n0) * MP;
    for (int i = t; i < 2304; i += 256) {
        int row = i / 36, c = i - row * 36;
        *(uint4*)(obase + row*MP + c*8) = *(const uint4*)(smem16 + row*296 + c*8);
    }
}

__global__ void gmax_reduce(const u32* __restrict__ gpart, u32* __restrict__ gmax)
{
    __shared__ u32 r[256];
    int t = threadIdx.x;
    r[t] = gpart[t]; __syncthreads();
    for (int s = 128; s; s >>= 1) { if (t < s) r[t] = max(r[t], r[t + s]); __syncthreads(); }
    if (t == 0) *gmax = r[0];
}

// ---------------------------------------------------------------------------
// Phase A: per-chunk S^T[d][m] = sum_n V[n][d]*K[n][m] via MFMA; VT row 64 =
// ones gives z[m] = sum_n K[n][m]. Output Sloc[chunk][65][288] fp32.
// LDS: KT half [288][72] (transposed K), VT [80][136] (transposed V + ones).
// ---------------------------------------------------------------------------
__global__ __launch_bounds__(256)
void chunk_ST(const u16* __restrict__ Kp, const u16* __restrict__ Vb,
              float* __restrict__ Sloc)
{
    int bhc = blockIdx.x;             // 1024
    int bh = bhc >> 5, c = bhc & (NC - 1);
    int b = bh >> 4, h = bh & 15;
    int t = threadIdx.x, w = t >> 6, lane = t & 63;
    int quad = lane >> 4, l16 = lane & 15;
    int n0 = c * CH;

    __shared__ __align__(16) u16 KTs[288*72];   // 41472 B
    __shared__ __align__(16) u16 VTs[80*136];   // 21760 B

    // stage VT (transposed V), ones row 64, zero rows 65..79
    {
        int d0 = (t >> 5) * 8, nb = (t & 31) * 4;
        const u16* vb2 = Vb + ((size_t)(b*NSEQ + n0 + nb)) * DM + h*DH + d0;
        uint4 r0 = *(const uint4*)(vb2);
        uint4 r1 = *(const uint4*)(vb2 + DM);
        uint4 r2 = *(const uint4*)(vb2 + 2*DM);
        uint4 r3 = *(const uint4*)(vb2 + 3*DM);
        const u32* a0 = (const u32*)&r0; const u32* a1 = (const u32*)&r1;
        const u32* a2 = (const u32*)&r2; const u32* a3 = (const u32*)&r3;
        #pragma unroll
        for (int e = 0; e < 8; ++e) {
            u32 w0 = a0[e>>1], w1 = a1[e>>1], w2 = a2[e>>1], w3 = a3[e>>1];
            u32 lo2, hi2;
            if (e & 1) { lo2 = (w0 >> 16) | (w1 & 0xFFFF0000u); hi2 = (w2 >> 16) | (w3 & 0xFFFF0000u); }
            else       { lo2 = (w0 & 0xFFFFu) | (w1 << 16);     hi2 = (w2 & 0xFFFFu) | (w3 << 16); }
            uint2 uu; uu.x = lo2; uu.y = hi2;
            *(uint2*)&VTs[(d0 + e)*136 + nb] = uu;
        }
        if (t < 128) VTs[64*136 + t] = 0x3F80u;      // ones row (bf16 1.0)
        if (t < 255) {                                // zero rows 65..79
            int rr = 65 + t/17, cc2 = t - (t/17)*17;
            uint4 z4 = (uint4){0,0,0,0};
            *(uint4*)&VTs[rr*136 + cc2*8] = z4;
        }
    }

    f32x4 am[18], az[5];
    #pragma unroll
    for (int mt = 0; mt < 18; ++mt) am[mt] = (f32x4){0.f,0.f,0.f,0.f};
    #pragma unroll
    for (int j = 0; j < 5; ++j) az[j] = (f32x4){0.f,0.f,0.f,0.f};

    const u16* kbase = Kp + ((size_t)bh * NSEQ + n0) * MP;
    for (int h2 = 0; h2 < 2; ++h2) {
        __syncthreads();
        // stage KT half: [288 m][64 n], 4-row packed b64 writes
        for (int i = t; i < 576; i += 256) {
            int nb4 = (i & 15) * 4, m0 = (i >> 4) * 8;
            const u16* kb = kbase + (size_t)(h2*64 + nb4) * MP + m0;
            uint4 r0 = *(const uint4*)(kb);
            uint4 r1 = *(const uint4*)(kb + MP);
            uint4 r2 = *(const uint4*)(kb + 2*MP);
            uint4 r3 = *(const uint4*)(kb + 3*MP);
            const u32* a0 = (const u32*)&r0; const u32* a1 = (const u32*)&r1;
            const u32* a2 = (const u32*)&r2; const u32* a3 = (const u32*)&r3;
            #pragma unroll
            for (int e = 0; e < 8; ++e) {
                u32 w0 = a0[e>>1], w1 = a1[e>>1], w2 = a2[e>>1], w3 = a3[e>>1];
                u32 lo2, hi2;
                if (e & 1) { lo2 = (w0 >> 16) | (w1 & 0xFFFF0000u); hi2 = (w2 >> 16) | (w3 & 0xFFFF0000u); }
                else       { lo2 = (w0 & 0xFFFFu) | (w1 << 16);     hi2 = (w2 & 0xFFFFu) | (w3 << 16); }
                uint2 uu; uu.x = lo2; uu.y = hi2;
                *(uint2*)&KTs[(m0 + e)*72 + nb4] = uu;
            }
        }
        __syncthreads();
        #pragma unroll
        for (int ks = 0; ks < 2; ++ks) {
            int nof = h2*64 + ks*32 + quad*8;
            bf16x8 aw = *(const bf16x8*)&VTs[(w*16 + l16)*136 + nof];
            bf16x8 a4 = *(const bf16x8*)&VTs[(64 + l16)*136 + nof];
            #pragma unroll
            for (int mt = 0; mt < 18; ++mt) {
                bf16x8 bk = *(const bf16x8*)&KTs[(mt*16 + l16)*72 + ks*32 + quad*8];
                am[mt] = __builtin_amdgcn_mfma_f32_16x16x32_bf16(aw, bk, am[mt], 0, 0, 0);
            }
            #pragma unroll
            for (int j = 0; j < 5; ++j) {
                int mtz = w + 4*j;
                if (mtz < 18) {
                    bf16x8 bk = *(const bf16x8*)&KTs[(mtz*16 + l16)*72 + ks*32 + quad*8];
                    az[j] = __builtin_amdgcn_mfma_f32_16x16x32_bf16(a4, bk, az[j], 0, 0, 0);
                }
            }
        }
    }

    float* sb = Sloc + (size_t)bhc * SROW;
    #pragma unroll
    for (int mt = 0; mt < 18; ++mt)
        #pragma unroll
        for (int r = 0; r < 4; ++r)
            sb[(size_t)(w*16 + quad*4 + r) * MP + mt*16 + l16] = am[mt][r];
    if (quad == 0) {
        #pragma unroll
        for (int j = 0; j < 5; ++j) {
            int mtz = w + 4*j;
            if (mtz < 18) sb[(size_t)64 * MP + mtz*16 + l16] = az[j][0];
        }
    }
}

// ---------------------------------------------------------------------------
// Phase B: in-place exclusive prefix over 32 chunks per (b,h).
// Rows 0..63 -> packed bf16 hi|lo<<16 in the same u32 slot; row 64 -> z+CEPS f32.
// ---------------------------------------------------------------------------
__global__ __launch_bounds__(256)
void chunk_prefix(float* __restrict__ Sloc)
{
    int gid = blockIdx.x * 256 + threadIdx.x;   // < 32*SROW = 599040 exactly
    int bh = gid / SROW;
    int rem = gid - bh * SROW;
    int row = rem / MP;
    size_t base = (size_t)bh * NC * SROW + rem;
    float run = 0.f;
    if (row < 64) {
        #pragma unroll 4
        for (int c2 = 0; c2 < NC; ++c2) {
            size_t o = base + (size_t)c2 * SROW;
            float v = Sloc[o];
            u16 hb = f2b(run);
            u16 lb = f2b(run - b2f(hb));
            ((u32*)Sloc)[o] = (u32)hb | ((u32)lb << 16);
            run += v;
        }
    } else {
        #pragma unroll 4
        for (int c2 = 0; c2 < NC; ++c2) {
            size_t o = base + (size_t)c2 * SROW;
            float v = Sloc[o];
            Sloc[o] = run + CEPS;
            run += v;
        }
    }
}

// ---------------------------------------------------------------------------
// Phase C: MFMA causal chunk attention. Block = one 128-token chunk, 4 waves.
// Wave w owns i-tiles {w, 7-w}. P^T = K.Q^T (swapped, both m-contiguous),
// fp32 rowsum for den, masked P -> bf16 LDS; PV + carry GEMMs via MFMA.
// ---------------------------------------------------------------------------
__global__ __launch_bounds__(256)
void scan_mfma(const u16* __restrict__ Qp, const u16* __restrict__ Kp,
               const u16* __restrict__ Vb, const float* __restrict__ Sp,
               u16* __restrict__ attn)
{
    int bhc = blockIdx.x;             // 1024
    int bh = bhc >> 5, c = bhc & (NC - 1);
    int b = bh >> 4, h = bh & 15;
    int t = threadIdx.x, w = t >> 6, lane = t & 63;
    int quad = lane >> 4, l16 = lane & 15;
    int n0 = c * CH;
    int it0 = w, it1 = 7 - w;

    __shared__ __align__(16) u16 R1s[9472];    // K quarter [32][296] -> VT [64][136]
    __shared__ __align__(16) u16 R2s[18944];   // P [128][136] -> STb [64][296]

    // zero P region (upper-triangle tiles never written)
    for (int i = t; i < 2176; i += 256) ((uint4*)R2s)[i] = (uint4){0,0,0,0};

    // Q fragments for both i-tiles (reused by QK^T as B and carry as A)
    bf16x8 q0[9], q1[9];
    {
        const u16* qa = Qp + ((size_t)bh * NSEQ + n0 + it0*16 + l16) * MP + quad*8;
        const u16* qb = Qp + ((size_t)bh * NSEQ + n0 + it1*16 + l16) * MP + quad*8;
        #pragma unroll
        for (int s = 0; s < 9; ++s) {
            q0[s] = *(const bf16x8*)(qa + s*32);
            q1[s] = *(const bf16x8*)(qb + s*32);
        }
    }

    float denw0 = 0.f, denw1 = 0.f;
    const u16* kbase = Kp + ((size_t)bh * NSEQ + n0) * MP;

    for (int qt = 0; qt < 4; ++qt) {
        __syncthreads();
        for (int i = t; i < 1152; i += 256) {
            int rr = i / 36, cc = i - rr * 36;
            *(uint4*)&R1s[rr*296 + cc*8] =
                *(const uint4*)(kbase + (size_t)(qt*32 + rr) * MP + cc*8);
        }
        __syncthreads();
        #pragma unroll
        for (int jj = 0; jj < 2; ++jj) {
            int jt = qt*2 + jj;
            #pragma unroll
            for (int itx = 0; itx < 2; ++itx) {
                int it = itx ? it1 : it0;
                if (jt <= it) {
                    f32x4 acc = (f32x4){0.f,0.f,0.f,0.f};
                    #pragma unroll
                    for (int s = 0; s < 9; ++s) {
                        bf16x8 kf = *(const bf16x8*)&R1s[(jj*16 + l16)*296 + s*32 + quad*8];
                        acc = __builtin_amdgcn_mfma_f32_16x16x32_bf16(
                            kf, itx ? q1[s] : q0[s], acc, 0, 0, 0);
                    }
                    int ig = it*16 + l16;
                    float rs = 0.f;
                    #pragma unroll
                    for (int r = 0; r < 4; ++r) {
                        int jg = jt*16 + quad*4 + r;
                        float pv = (jg <= ig) ? acc[r] : 0.f;
                        rs += pv;
                        R2s[ig*136 + jg] = f2b(pv);
                    }
                    if (itx) denw1 += rs; else denw0 += rs;
                }
            }
        }
    }

    __syncthreads();
    // stage VT (transposed V) into R1
    {
        int d0 = (t >> 5) * 8, nb = (t & 31) * 4;
        const u16* vb2 = Vb + ((size_t)(b*NSEQ + n0 + nb)) * DM + h*DH + d0;
        uint4 r0 = *(const uint4*)(vb2);
        uint4 r1 = *(const uint4*)(vb2 + DM);
        uint4 r2 = *(const uint4*)(vb2 + 2*DM);
        uint4 r3 = *(const uint4*)(vb2 + 3*DM);
        const u32* a0 = (const u32*)&r0; const u32* a1 = (const u32*)&r1;
        const u32* a2 = (const u32*)&r2; const u32* a3 = (const u32*)&r3;
        #pragma unroll
        for (int e = 0; e < 8; ++e) {
            u32 w0 = a0[e>>1], w1 = a1[e>>1], w2 = a2[e>>1], w3 = a3[e>>1];
            u32 lo2, hi2;
            if (e & 1) { lo2 = (w0 >> 16) | (w1 & 0xFFFF0000u); hi2 = (w2 >> 16) | (w3 & 0xFFFF0000u); }
            else       { lo2 = (w0 & 0xFFFFu) | (w1 << 16);     hi2 = (w2 & 0xFFFFu) | (w3 << 16); }
            uint2 uu; uu.x = lo2; uu.y = hi2;
            *(uint2*)&R1s[(d0 + e)*136 + nb] = uu;
        }
    }
    __syncthreads();

    // PV: out[i][d] += P[i][j] * VT[d][j]
    f32x4 pacc[2][4];
    #pragma unroll
    for (int i = 0; i < 2; ++i)
        #pragma unroll
        for (int j = 0; j < 4; ++j) pacc[i][j] = (f32x4){0.f,0.f,0.f,0.f};
    int ns0 = (it0 + 2) >> 1, ns1 = (it1 + 2) >> 1;
    #pragma unroll
    for (int ks = 0; ks < 4; ++ks) {
        bool u0 = ks < ns0, u1 = ks < ns1;
        bf16x8 p0 = {}, p1 = {};
        if (u0) p0 = *(const bf16x8*)&R2s[(it0*16 + l16)*136 + ks*32 + quad*8];
        if (u1) p1 = *(const bf16x8*)&R2s[(it1*16 + l16)*136 + ks*32 + quad*8];
        #pragma unroll
        for (int ct = 0; ct < 4; ++ct) {
            bf16x8 vf = *(const bf16x8*)&R1s[(ct*16 + l16)*136 + ks*32 + quad*8];
            if (u0) pacc[0][ct] = __builtin_amdgcn_mfma_f32_16x16x32_bf16(p0, vf, pacc[0][ct], 0, 0, 0);
            if (u1) pacc[1][ct] = __builtin_amdgcn_mfma_f32_16x16x32_bf16(p1, vf, pacc[1][ct], 0, 0, 0);
        }
    }

    // carry: out[i][d] += Q[i][m] * S^T[d][m], hi then lo pass
    f32x4 cacc[2][4];
    #pragma unroll
    for (int i = 0; i < 2; ++i)
        #pragma unroll
        for (int j = 0; j < 4; ++j) cacc[i][j] = (f32x4){0.f,0.f,0.f,0.f};
    const u32* spw = (const u32*)Sp + (size_t)bhc * SROW;
    #pragma unroll
    for (int pass = 0; pass < 2; ++pass) {
        __syncthreads();
        for (int i = t; i < 4608; i += 256) {
            int rr = i / 72, cc = i - rr * 72;
            uint4 v = *(const uint4*)(spw + (size_t)rr * MP + cc*4);
            u32 lo2, hi2;
            if (pass) { lo2 = (v.x >> 16) | (v.y & 0xFFFF0000u); hi2 = (v.z >> 16) | (v.w & 0xFFFF0000u); }
            else      { lo2 = (v.x & 0xFFFFu) | (v.y << 16);     hi2 = (v.z & 0xFFFFu) | (v.w << 16); }
            uint2 uu; uu.x = lo2; uu.y = hi2;
            *(uint2*)&R2s[rr*296 + cc*4] = uu;
        }
        __syncthreads();
        #pragma unroll
        for (int s = 0; s < 9; ++s)
            #pragma unroll
            for (int ct = 0; ct < 4; ++ct) {
                bf16x8 sf = *(const bf16x8*)&R2s[(ct*16 + l16)*296 + s*32 + quad*8];
                cacc[0][ct] = __builtin_amdgcn_mfma_f32_16x16x32_bf16(q0[s], sf, cacc[0][ct], 0, 0, 0);
                cacc[1][ct] = __builtin_amdgcn_mfma_f32_16x16x32_bf16(q1[s], sf, cacc[1][ct], 0, 0, 0);
            }
    }

    // den carry: q . (z_prefix + CEPS), scalar (zc fp32 from row 64)
    float dc0 = 0.f, dc1 = 0.f;
    {
        const float* zc = Sp + (size_t)bhc * SROW + (size_t)64 * MP + quad*8;
        #pragma unroll
        for (int s = 0; s < 9; ++s) {
            f32x4 za = *(const f32x4*)(zc + s*32);
            f32x4 zb = *(const f32x4*)(zc + s*32 + 4);
            #pragma unroll
            for (int e = 0; e < 4; ++e) {
                dc0 += (float)q0[s][e] * za[e];
                dc0 += (float)q0[s][e+4] * zb[e];
                dc1 += (float)q1[s][e] * za[e];
                dc1 += (float)q1[s][e+4] * zb[e];
            }
        }
    }
    dc0 += __shfl_xor(dc0, 16, 64); dc0 += __shfl_xor(dc0, 32, 64);
    dc1 += __shfl_xor(dc1, 16, 64); dc1 += __shfl_xor(dc1, 32, 64);
    denw0 += __shfl_xor(denw0, 16, 64); denw0 += __shfl_xor(denw0, 32, 64);
    denw1 += __shfl_xor(denw1, 16, 64); denw1 += __shfl_xor(denw1, 32, 64);
    float den0 = denw0 + dc0, den1 = denw1 + dc1;

    // output
    u16* ab = attn + ((size_t)(b*NSEQ + n0)) * DM + h*DH;
    #pragma unroll
    for (int itx = 0; itx < 2; ++itx) {
        int it = itx ? it1 : it0;
        float dv = itx ? den1 : den0;
        #pragma unroll
        for (int r = 0; r < 4; ++r) {
            float deno = __shfl(dv, (lane & 48) + quad*4 + r, 64);
            int row = it*16 + quad*4 + r;
            #pragma unroll
            for (int ct = 0; ct < 4; ++ct) {
                float ov = (pacc[itx][ct][r] + cacc[itx][ct][r]) / deno;
                ab[(size_t)row * DM + ct*16 + l16] = f2b(ov);
            }
        }
    }
}

// ---------------------------------------------------------------------------
extern "C" void kernel_launch(void* const* d_in, const int* in_sizes, int n_in,
                              void* d_out, int out_size, void* d_ws, size_t ws_size,
                              hipStream_t stream)
{
    (void)n_in; (void)out_size; (void)ws_size;
    const void* x  = d_in[0];
    const void* Wq = d_in[1]; const void* bq = d_in[2];
    const void* Wk = d_in[3]; const void* bk = d_in[4];
    const void* Wv = d_in[5]; const void* bv = d_in[6];
    const void* Wo = d_in[7]; const void* bo = d_in[8];
    const void* proj = d_in[9];

    char* ws = (char*)d_ws;
    size_t off = 0;
    auto alloc = [&](size_t bytes) -> char* {
        char* p = ws + off; off += (bytes + 255) & ~(size_t)255; return p;
    };
    // QKf (33.5 MB, dead after feat K) overlays Sloc (76.7 MB, used after)
    size_t qkfBytes  = (size_t)NROWS * DM * 4;
    size_t slocBytes = (size_t)(B_ * H_ * NC) * SROW * 4;
    char*  ov0  = alloc(slocBytes > qkfBytes ? slocBytes : qkfBytes);
    float* QKf  = (float*)ov0;
    float* Sloc = (float*)ov0;
    u16*   Vb   = (u16*)alloc((size_t)NROWS * DM * 2);
    u16*   Qp   = (u16*)alloc((size_t)NHROWS * MP * 2);
    u16*   Kp   = (u16*)alloc((size_t)NHROWS * MP * 2);
    u16*   projC= (u16*)alloc((size_t)MP * DH * 2);
    u16*   Wb   = (u16*)alloc((size_t)DM * DM * 2);
    u16*   bqb  = (u16*)alloc(DM * 2);
    u16*   bkb  = (u16*)alloc(DM * 2);
    u16*   bvb  = (u16*)alloc(DM * 2);
    u16*   bob  = (u16*)alloc(DM * 2);
    u32*   flags= (u32*)alloc(16 * 4);
    u32*   gmax = (u32*)alloc(256);
    u32*   gpart= (u32*)alloc(256 * 4);
    char*  xatt = alloc((size_t)NROWS * DM * 2);
    u16*   xb   = (u16*)xatt;    // alias: xb dead after gemm K
    u16*   attn = (u16*)xatt;    // scan writes afterwards

    const int nW = DM * DM, nX = NROWS * DM;
    dim3 gg(NROWS / 128, DM / 128);

    DetectArgs da;
    for (int i = 0; i < 10; ++i) {
        int n = in_sizes[i];
        int nwords = n / 2; if (nwords > 4096) nwords = 4096;
        da.p[i] = (const u32*)d_in[i];
        da.nw[i] = nwords;
    }
    detect_all<<<10, 256, 0, stream>>>(da, flags);

    prep2<<<(MP * DH + 255) / 256, 256, 0, stream>>>(proj, projC, gpart, gmax, flags + 9);
    conv_kernel<<<(nX + 2047) / 2048, 256, 0, stream>>>(x, xb, nX, flags + 0);
    conv_kernel<<<1, 256, 0, stream>>>(bq, bqb, DM, flags + 2);
    conv_kernel<<<1, 256, 0, stream>>>(bk, bkb, DM, flags + 4);
    conv_kernel<<<1, 256, 0, stream>>>(bv, bvb, DM, flags + 6);
    conv_kernel<<<1, 256, 0, stream>>>(bo, bob, DM, flags + 8);

    conv_kernel<<<(nW + 2047) / 2048, 256, 0, stream>>>(Wv, Wb, nW, flags + 5);
    gemm_nt<1><<<gg, 256, 0, stream>>>(xb, Wb, bvb, Vb);

    conv_kernel<<<(nW + 2047) / 2048, 256, 0, stream>>>(Wq, Wb, nW, flags + 1);
    gemm_nt<0><<<gg, 256, 0, stream>>>(xb, Wb, bqb, QKf);
    feat_mfma<0><<<NHROWS / 64, 256, 0, stream>>>(QKf, projC, Qp, gpart, gmax);

    conv_kernel<<<(nW + 2047) / 2048, 256, 0, stream>>>(Wk, Wb, nW, flags + 3);
    gemm_nt<0><<<gg, 256, 0, stream>>>(xb, Wb, bkb, QKf);
    feat_mfma<1><<<NHROWS / 64, 256, 0, stream>>>(QKf, projC, Kp, gpart, gmax);
    gmax_reduce<<<1, 256, 0, stream>>>(gpart, gmax);
    feat_mfma<2><<<NHROWS / 64, 256, 0, stream>>>(QKf, projC, Kp, gpart, gmax);

    // MFMA chunk-parallel causal scan
    chunk_ST<<<B_ * H_ * NC, 256, 0, stream>>>(Kp, Vb, Sloc);
    chunk_prefix<<<(B_ * H_ * SROW) / 256, 256, 0, stream>>>(Sloc);
    scan_mfma<<<B_ * H_ * NC, 256, 0, stream>>>(Qp, Kp, Vb, Sloc, attn);

    conv_kernel<<<(nW + 2047) / 2048, 256, 0, stream>>>(Wo, Wb, nW, flags + 7);
    // OUTPUT IS FP32 (reference's output dtype, per harness instructions).
    gemm_nt<0><<<gg, 256, 0, stream>>>(attn, Wb, bob, d_out);
}

// Round 5
// 455.845 us; speedup vs baseline: 30.9117x; 1.0394x over previous
//
#include <hip/hip_runtime.h>

#define B_    2
#define NSEQ  4096
#define DM    1024
#define H_    16
#define DH    64
#define MF    266
#define MP    288          // padded feature count, 9 x 32 (pads are zero)
#define NROWS (B_*NSEQ)    // 8192
#define NHROWS (B_*H_*NSEQ) // 131072
#define RATIO 0.06131393394849658f   // 266^-0.5
#define DNORM 0.3535533905932738f    // 64^-0.25
#define KEPS  1e-4f
#define CEPS  1e-6f

// chunked causal scan geometry
#define CH    128                 // tokens per chunk
#define NC    32                  // chunks per (b,h) = NSEQ/CH
#define SROW  (65*MP)             // per-chunk state: 64 S^T rows + 1 z row = 18720

#define AS1 __attribute__((address_space(1)))
#define AS3 __attribute__((address_space(3)))

typedef unsigned short u16;
typedef unsigned int   u32;

typedef __bf16 bf16x8 __attribute__((ext_vector_type(8)));
typedef float  f32x4  __attribute__((ext_vector_type(4)));

__device__ __forceinline__ float b2f(u16 u){ u32 x = ((u32)u) << 16; return __builtin_bit_cast(float, x); }
__device__ __forceinline__ u16 f2b(float f){
    u32 x = __builtin_bit_cast(u32, f);
    u32 r = x + 0x7fffu + ((x >> 16) & 1u);
    return (u16)(r >> 16);
}
__device__ __forceinline__ u32 enc_max(float f){ u32 b = __builtin_bit_cast(u32, f); return (b & 0x80000000u) ? ~b : (b | 0x80000000u); }
__device__ __forceinline__ float dec_max(u32 u){ u32 b = (u & 0x80000000u) ? (u & 0x7fffffffu) : ~u; return __builtin_bit_cast(float, b); }

// ---------------------------------------------------------------------------
// Per-input dtype detection, all 10 inputs in one launch. flag 1=bf16, 0=fp32.
// ---------------------------------------------------------------------------
struct DetectArgs { const u32* p[10]; int nw[10]; };

__global__ void detect_all(DetectArgs a, u32* __restrict__ flags)
{
    __shared__ int cnt[256];
    int k = blockIdx.x;
    const u32* src = a.p[k];
    int nwords = a.nw[k];
    int t = threadIdx.x; int c = 0;
    for (int i = t; i < nwords; i += 256) {
        u32 w = src[i];
        int ea = (int)((w >> 7)  & 0xFF);
        int eb = (int)((w >> 23) & 0xFF);
        c += (ea >= 112 && ea <= 143) ? 1 : 0;
        c += (eb >= 112 && eb <= 143) ? 1 : 0;
    }
    cnt[t] = c; __syncthreads();
    for (int s = 128; s; s >>= 1) { if (t < s) cnt[t] += cnt[t + s]; __syncthreads(); }
    if (t == 0) flags[k] = (cnt[0] >= (nwords * 3) / 2) ? 1u : 0u;  // 75% of 2*nwords
}

// ---------------------------------------------------------------------------
// Convert n elements (n % 8 == 0) from src (fp32 or bf16 per its flag) to bf16.
// ---------------------------------------------------------------------------
__global__ __launch_bounds__(256)
void conv_kernel(const void* __restrict__ src, u16* __restrict__ dst, int n,
                 const u32* __restrict__ gflag)
{
    int i = (blockIdx.x * 256 + threadIdx.x) * 8;
    if (i >= n) return;
    if (*gflag) {
        *(uint4*)(dst + i) = *(const uint4*)((const u16*)src + i);
    } else {
        const float* s = (const float*)src + i;
        u16 tmp[8];
        #pragma unroll
        for (int j = 0; j < 8; ++j) tmp[j] = f2b(s[j]);
        *(uint4*)(dst + i) = *(uint4*)tmp;
    }
}

// ---------------------------------------------------------------------------
// GEMM (m97 structure): C[r][c] = sum_k A[r][k] * W[c][k] + bias[c].
// 128x128 tile, 4 waves, global_load_lds width=16 into LINEAR LDS [128][32],
// with pre-swizzled global source (cslot ^= row&3) so fragment ds_read_b128
// at row*64 + ((quad^(l16&3))<<4) is 2-way bank-aliased (free).
// ---------------------------------------------------------------------------
template<int OUT_BF16>
__global__ __launch_bounds__(256)
void gemm_nt(const u16* __restrict__ A, const u16* __restrict__ Bm,
             const u16* __restrict__ bias, void* __restrict__ C)
{
    const int K = DM, Nc = DM;
    __shared__ u16 As[128 * 32];   // 8 KiB, linear (gload_lds dest)
    __shared__ u16 Bs[128 * 32];
    int t = threadIdx.x;
    int wave = t >> 6, lane = t & 63;
    int wm = wave >> 1, wn = wave & 1;
    int quad = lane >> 4, l16 = lane & 15;
    int bm = blockIdx.x * 128, bn = blockIdx.y * 128;

    // per-lane staging source geometry: chunk c = wave*2+j covers rows c*16..+15
    int rA0 = (wave*2 + 0)*16 + (lane >> 2);
    int rA1 = (wave*2 + 1)*16 + (lane >> 2);
    int cs0 = ((lane & 3) ^ (rA0 & 3)) * 8;
    int cs1 = ((lane & 3) ^ (rA1 & 3)) * 8;
    const u16* a0 = A  + (size_t)(bm + rA0) * K + cs0;
    const u16* a1 = A  + (size_t)(bm + rA1) * K + cs1;
    const u16* b0 = Bm + (size_t)(bn + rA0) * K + cs0;
    const u16* b1 = Bm + (size_t)(bn + rA1) * K + cs1;
    u16* la0 = As + (wave*2 + 0)*512;   // 512 u16 = 1024 B per chunk
    u16* la1 = As + (wave*2 + 1)*512;
    u16* lb0 = Bs + (wave*2 + 0)*512;
    u16* lb1 = Bs + (wave*2 + 1)*512;

    f32x4 acc[4][4];
    #pragma unroll
    for (int i = 0; i < 4; ++i)
        #pragma unroll
        for (int j = 0; j < 4; ++j) acc[i][j] = (f32x4){0.f,0.f,0.f,0.f};

    for (int k0 = 0; k0 < K; k0 += 32) {
        __builtin_amdgcn_global_load_lds((const AS1 void*)(a0 + k0), (AS3 void*)la0, 16, 0, 0);
        __builtin_amdgcn_global_load_lds((const AS1 void*)(a1 + k0), (AS3 void*)la1, 16, 0, 0);
        __builtin_amdgcn_global_load_lds((const AS1 void*)(b0 + k0), (AS3 void*)lb0, 16, 0, 0);
        __builtin_amdgcn_global_load_lds((const AS1 void*)(b1 + k0), (AS3 void*)lb1, 16, 0, 0);
        __syncthreads();
        bf16x8 af[4], bfr[4];
        int qsw = (quad ^ (l16 & 3)) << 4;
        #pragma unroll
        for (int i = 0; i < 4; ++i) {
            af[i]  = *(const bf16x8*)((const char*)As + (wm*64 + i*16 + l16)*64 + qsw);
            bfr[i] = *(const bf16x8*)((const char*)Bs + (wn*64 + i*16 + l16)*64 + qsw);
        }
        #pragma unroll
        for (int i = 0; i < 4; ++i)
            #pragma unroll
            for (int j = 0; j < 4; ++j)
                acc[i][j] = __builtin_amdgcn_mfma_f32_16x16x32_bf16(af[i], bfr[j], acc[i][j], 0, 0, 0);
        __syncthreads();
    }
    #pragma unroll
    for (int i = 0; i < 4; ++i) {
        #pragma unroll
        for (int j = 0; j < 4; ++j) {
            int col = bn + wn*64 + j*16 + l16;
            float bv = b2f(bias[col]);
            #pragma unroll
            for (int r = 0; r < 4; ++r) {
                int row = bm + wm*64 + i*16 + quad*4 + r;
                float v = acc[i][j][r] + bv;
                if (OUT_BF16) ((u16*)C)[(size_t)row * Nc + col] = f2b(v);
                else          ((float*)C)[(size_t)row * Nc + col] = v;
            }
        }
    }
}

// ---------------------------------------------------------------------------
// prep2: projC[288][64]: bf16(proj[m][d]) for m<266, zeros for pad rows.
// ---------------------------------------------------------------------------
__global__ __launch_bounds__(256)
void prep2(const void* __restrict__ proj, u16* __restrict__ projC,
           u32* __restrict__ gpart, u32* __restrict__ gmax,
           const u32* __restrict__ gflag)
{
    int i = blockIdx.x * 256 + threadIdx.x;
    if (i < 256) gpart[i] = 0u;
    if (i == 256) *gmax = 0u;
    if (i < MP * DH) {
        u16 v = 0;
        if (i < MF * DH)
            v = (*gflag) ? ((const u16*)proj)[i] : f2b(((const float*)proj)[i]);
        projC[i] = v;
    }
}

// ---------------------------------------------------------------------------
// MFMA feature map. Block = 64 rows of one (b,h); 4 waves x 16 rows.
// ---------------------------------------------------------------------------
template<int MODE>
__global__ __launch_bounds__(256)
void feat_mfma(const float* __restrict__ X, const u16* __restrict__ projP,
               u16* __restrict__ OutP, u32* __restrict__ gpart,
               const u32* __restrict__ gmax)
{
    int blk = blockIdx.x;             // 0..2047
    int bh = blk >> 6, nt = blk & 63;
    int b = bh >> 4, h = bh & 15;
    int n0 = nt * 64;
    int t = threadIdx.x;
    int lane = t & 63, w = t >> 6;
    int quad = lane >> 4, l16 = lane & 15;

    __shared__ uint4 smemU[2368];     // max(proj 288*128B, out 64*296*2B) = 37888B
    u16* smem16 = (u16*)smemU;

    const float* xrow = X + ((size_t)(b * NSEQ + n0 + w*16 + l16)) * DM + h * DH;
    float va[2][8];
    #pragma unroll
    for (int ks = 0; ks < 2; ++ks) {
        float4 u0 = *(const float4*)(xrow + ks*32 + quad*8);
        float4 u1 = *(const float4*)(xrow + ks*32 + quad*8 + 4);
        va[ks][0]=u0.x; va[ks][1]=u0.y; va[ks][2]=u0.z; va[ks][3]=u0.w;
        va[ks][4]=u1.x; va[ks][5]=u1.y; va[ks][6]=u1.z; va[ks][7]=u1.w;
    }

    // stage proj into LDS, XOR-swizzled: row m at byte m*128, byte^((m&7)<<4)
    for (int i = t; i < 2304; i += 256) {
        int m = i >> 3, c = i & 7;
        uint4 v = *(const uint4*)(projP + m*64 + c*8);
        int dstb = m*128 + ((c*16) ^ ((m & 7) << 4));
        *(uint4*)((char*)smemU + dstb) = v;
    }

    bf16x8 ahi[2], alo[2];
    float sq = 0.f;
    #pragma unroll
    for (int ks = 0; ks < 2; ++ks) {
        #pragma unroll
        for (int i = 0; i < 8; ++i) {
            float v = va[ks][i] * DNORM;
            sq += v * v;
            u16 hb = f2b(v);
            float hv = b2f(hb);
            ahi[ks][i] = __builtin_bit_cast(__bf16, hb);
            alo[ks][i] = __builtin_bit_cast(__bf16, f2b(v - hv));
        }
    }
    sq += __shfl_xor(sq, 16, 64);
    sq += __shfl_xor(sq, 32, 64);
    float diag_my = 0.5f * sq;

    __syncthreads();                  // projS ready

    f32x4 acc[18];
    #pragma unroll
    for (int j = 0; j < 18; ++j) acc[j] = (f32x4){0.f,0.f,0.f,0.f};
    #pragma unroll
    for (int j = 0; j < 18; ++j) {
        int m = j*16 + l16;
        #pragma unroll
        for (int ks = 0; ks < 2; ++ks) {
            int off = m*128 + (((quad*16) + ks*64) ^ ((m & 7) << 4));
            bf16x8 bf = *(const bf16x8*)((const char*)smemU + off);
            acc[j] = __builtin_amdgcn_mfma_f32_16x16x32_bf16(ahi[ks], bf, acc[j], 0, 0, 0);
            acc[j] = __builtin_amdgcn_mfma_f32_16x16x32_bf16(alo[ks], bf, acc[j], 0, 0, 0);
        }
    }

    // per-row max over valid m: tiles 0..15 full; tile 16: l16<10; tile 17: pad
    float rmax[4];
    #pragma unroll
    for (int r = 0; r < 4; ++r) rmax[r] = -3.4e38f;
    #pragma unroll
    for (int j = 0; j < 16; ++j)
        #pragma unroll
        for (int r = 0; r < 4; ++r) rmax[r] = fmaxf(rmax[r], acc[j][r]);
    if (l16 < MF - 256) {
        #pragma unroll
        for (int r = 0; r < 4; ++r) rmax[r] = fmaxf(rmax[r], acc[16][r]);
    }
    #pragma unroll
    for (int s = 1; s < 16; s <<= 1)
        #pragma unroll
        for (int r = 0; r < 4; ++r)
            rmax[r] = fmaxf(rmax[r], __shfl_xor(rmax[r], s, 64));

    if (MODE == 1) {
        float wm2 = fmaxf(fmaxf(rmax[0], rmax[1]), fmaxf(rmax[2], rmax[3]));
        wm2 = fmaxf(wm2, __shfl_xor(wm2, 16, 64));
        wm2 = fmaxf(wm2, __shfl_xor(wm2, 32, 64));
        if (lane == 0) atomicMax(&gpart[blk & 255], enc_max(wm2));
        return;
    }

    float gstab = (MODE == 2) ? dec_max(*gmax) : 0.f;
    float dg[4];
    #pragma unroll
    for (int r = 0; r < 4; ++r) dg[r] = __shfl(diag_my, quad*4 + r, 64);

    __syncthreads();                  // all proj reads done; reuse LDS as outS

    #pragma unroll
    for (int j = 0; j < 18; ++j) {
        int m = j*16 + l16;
        #pragma unroll
        for (int r = 0; r < 4; ++r) {
            float stab = (MODE == 0) ? rmax[r] : gstab;
            float val = RATIO * (__expf(acc[j][r] - dg[r] - stab) + KEPS);
            u16 ov = (m < MF) ? f2b(val) : (u16)0;
            smem16[(w*16 + quad*4 + r) * 296 + m] = ov;
        }
    }
    __syncthreads();

    // coalesced store: 64 rows x 288 u16 (= 36 uint4 chunks per row)
    u16* obase = OutP + ((size_t)bh * NSEQ + n0) * MP;
    for (int i = t; i < 2304; i += 256) {
        int row = i / 36, c = i - row * 36;
        *(uint4*)(obase + row*MP + c*8) = *(const uint4*)(smem16 + row*296 + c*8);
    }
}

__global__ void gmax_reduce(const u32* __restrict__ gpart, u32* __restrict__ gmax)
{
    __shared__ u32 r[256];
    int t = threadIdx.x;
    r[t] = gpart[t]; __syncthreads();
    for (int s = 128; s; s >>= 1) { if (t < s) r[t] = max(r[t], r[t + s]); __syncthreads(); }
    if (t == 0) *gmax = r[0];
}

// ---------------------------------------------------------------------------
// Phase A: per-chunk S^T[d][m] = sum_n V[n][d]*K[n][m] via MFMA; VT row 64 =
// ones gives z[m] = sum_n K[n][m]. Output Sloc[chunk][65][288] fp32.
// ---------------------------------------------------------------------------
__global__ __launch_bounds__(256)
void chunk_ST(const u16* __restrict__ Kp, const u16* __restrict__ Vb,
              float* __restrict__ Sloc)
{
    int bhc = blockIdx.x;             // 1024
    int bh = bhc >> 5, c = bhc & (NC - 1);
    int b = bh >> 4, h = bh & 15;
    int t = threadIdx.x, w = t >> 6, lane = t & 63;
    int quad = lane >> 4, l16 = lane & 15;
    int n0 = c * CH;

    __shared__ __align__(16) u16 KTs[288*72];   // 41472 B
    __shared__ __align__(16) u16 VTs[80*136];   // 21760 B

    // stage VT (transposed V), ones row 64, zero rows 65..79
    {
        int d0 = (t >> 5) * 8, nb = (t & 31) * 4;
        const u16* vb2 = Vb + ((size_t)(b*NSEQ + n0 + nb)) * DM + h*DH + d0;
        uint4 r0 = *(const uint4*)(vb2);
        uint4 r1 = *(const uint4*)(vb2 + DM);
        uint4 r2 = *(const uint4*)(vb2 + 2*DM);
        uint4 r3 = *(const uint4*)(vb2 + 3*DM);
        const u32* a0 = (const u32*)&r0; const u32* a1 = (const u32*)&r1;
        const u32* a2 = (const u32*)&r2; const u32* a3 = (const u32*)&r3;
        #pragma unroll
        for (int e = 0; e < 8; ++e) {
            u32 w0 = a0[e>>1], w1 = a1[e>>1], w2 = a2[e>>1], w3 = a3[e>>1];
            u32 lo2, hi2;
            if (e & 1) { lo2 = (w0 >> 16) | (w1 & 0xFFFF0000u); hi2 = (w2 >> 16) | (w3 & 0xFFFF0000u); }
            else       { lo2 = (w0 & 0xFFFFu) | (w1 << 16);     hi2 = (w2 & 0xFFFFu) | (w3 << 16); }
            uint2 uu; uu.x = lo2; uu.y = hi2;
            *(uint2*)&VTs[(d0 + e)*136 + nb] = uu;
        }
        if (t < 128) VTs[64*136 + t] = 0x3F80u;      // ones row (bf16 1.0)
        if (t < 255) {                                // zero rows 65..79
            int rr = 65 + t/17, cc2 = t - (t/17)*17;
            uint4 z4 = (uint4){0,0,0,0};
            *(uint4*)&VTs[rr*136 + cc2*8] = z4;
        }
    }

    f32x4 am[18], az[5];
    #pragma unroll
    for (int mt = 0; mt < 18; ++mt) am[mt] = (f32x4){0.f,0.f,0.f,0.f};
    #pragma unroll
    for (int j = 0; j < 5; ++j) az[j] = (f32x4){0.f,0.f,0.f,0.f};

    const u16* kbase = Kp + ((size_t)bh * NSEQ + n0) * MP;
    for (int h2 = 0; h2 < 2; ++h2) {
        __syncthreads();
        // stage KT half: [288 m][64 n], 4-row packed b64 writes
        for (int i = t; i < 576; i += 256) {
            int nb4 = (i & 15) * 4, m0 = (i >> 4) * 8;
            const u16* kb = kbase + (size_t)(h2*64 + nb4) * MP + m0;
            uint4 r0 = *(const uint4*)(kb);
            uint4 r1 = *(const uint4*)(kb + MP);
            uint4 r2 = *(const uint4*)(kb + 2*MP);
            uint4 r3 = *(const uint4*)(kb + 3*MP);
            const u32* a0 = (const u32*)&r0; const u32* a1 = (const u32*)&r1;
            const u32* a2 = (const u32*)&r2; const u32* a3 = (const u32*)&r3;
            #pragma unroll
            for (int e = 0; e < 8; ++e) {
                u32 w0 = a0[e>>1], w1 = a1[e>>1], w2 = a2[e>>1], w3 = a3[e>>1];
                u32 lo2, hi2;
                if (e & 1) { lo2 = (w0 >> 16) | (w1 & 0xFFFF0000u); hi2 = (w2 >> 16) | (w3 & 0xFFFF0000u); }
                else       { lo2 = (w0 & 0xFFFFu) | (w1 << 16);     hi2 = (w2 & 0xFFFFu) | (w3 << 16); }
                uint2 uu; uu.x = lo2; uu.y = hi2;
                *(uint2*)&KTs[(m0 + e)*72 + nb4] = uu;
            }
        }
        __syncthreads();
        #pragma unroll
        for (int ks = 0; ks < 2; ++ks) {
            int nof = h2*64 + ks*32 + quad*8;
            bf16x8 aw = *(const bf16x8*)&VTs[(w*16 + l16)*136 + nof];
            bf16x8 a4 = *(const bf16x8*)&VTs[(64 + l16)*136 + nof];
            #pragma unroll
            for (int mt = 0; mt < 18; ++mt) {
                bf16x8 bk = *(const bf16x8*)&KTs[(mt*16 + l16)*72 + ks*32 + quad*8];
                am[mt] = __builtin_amdgcn_mfma_f32_16x16x32_bf16(aw, bk, am[mt], 0, 0, 0);
            }
            #pragma unroll
            for (int j = 0; j < 5; ++j) {
                int mtz = w + 4*j;
                if (mtz < 18) {
                    bf16x8 bk = *(const bf16x8*)&KTs[(mtz*16 + l16)*72 + ks*32 + quad*8];
                    az[j] = __builtin_amdgcn_mfma_f32_16x16x32_bf16(a4, bk, az[j], 0, 0, 0);
                }
            }
        }
    }

    float* sb = Sloc + (size_t)bhc * SROW;
    #pragma unroll
    for (int mt = 0; mt < 18; ++mt)
        #pragma unroll
        for (int r = 0; r < 4; ++r)
            sb[(size_t)(w*16 + quad*4 + r) * MP + mt*16 + l16] = am[mt][r];
    if (quad == 0) {
        #pragma unroll
        for (int j = 0; j < 5; ++j) {
            int mtz = w + 4*j;
            if (mtz < 18) sb[(size_t)64 * MP + mtz*16 + l16] = az[j][0];
        }
    }
}

// ---------------------------------------------------------------------------
// Phase B: in-place exclusive prefix over 32 chunks per (b,h).
// Rows 0..63 -> packed bf16 hi|lo<<16 in the same u32 slot; row 64 -> z+CEPS f32.
// ---------------------------------------------------------------------------
__global__ __launch_bounds__(256)
void chunk_prefix(float* __restrict__ Sloc)
{
    int gid = blockIdx.x * 256 + threadIdx.x;   // < 32*SROW = 599040 exactly
    int bh = gid / SROW;
    int rem = gid - bh * SROW;
    int row = rem / MP;
    size_t base = (size_t)bh * NC * SROW + rem;
    float run = 0.f;
    if (row < 64) {
        #pragma unroll 4
        for (int c2 = 0; c2 < NC; ++c2) {
            size_t o = base + (size_t)c2 * SROW;
            float v = Sloc[o];
            u16 hb = f2b(run);
            u16 lb = f2b(run - b2f(hb));
            ((u32*)Sloc)[o] = (u32)hb | ((u32)lb << 16);
            run += v;
        }
    } else {
        #pragma unroll 4
        for (int c2 = 0; c2 < NC; ++c2) {
            size_t o = base + (size_t)c2 * SROW;
            float v = Sloc[o];
            Sloc[o] = run + CEPS;
            run += v;
        }
    }
}

// ---------------------------------------------------------------------------
// Phase C: MFMA causal chunk attention. Block = one 128-token chunk, 4 waves.
// ---------------------------------------------------------------------------
__global__ __launch_bounds__(256)
void scan_mfma(const u16* __restrict__ Qp, const u16* __restrict__ Kp,
               const u16* __restrict__ Vb, const float* __restrict__ Sp,
               u16* __restrict__ attn)
{
    int bhc = blockIdx.x;             // 1024
    int bh = bhc >> 5, c = bhc & (NC - 1);
    int b = bh >> 4, h = bh & 15;
    int t = threadIdx.x, w = t >> 6, lane = t & 63;
    int quad = lane >> 4, l16 = lane & 15;
    int n0 = c * CH;
    int it0 = w, it1 = 7 - w;

    __shared__ __align__(16) u16 R1s[9472];    // K quarter [32][296] -> VT [64][136]
    __shared__ __align__(16) u16 R2s[18944];   // P [128][136] -> STb [64][296]

    // zero P region (upper-triangle tiles never written)
    for (int i = t; i < 2176; i += 256) ((uint4*)R2s)[i] = (uint4){0,0,0,0};

    // Q fragments for both i-tiles (reused by QK^T as B and carry as A)
    bf16x8 q0[9], q1[9];
    {
        const u16* qa = Qp + ((size_t)bh * NSEQ + n0 + it0*16 + l16) * MP + quad*8;
        const u16* qb = Qp + ((size_t)bh * NSEQ + n0 + it1*16 + l16) * MP + quad*8;
        #pragma unroll
        for (int s = 0; s < 9; ++s) {
            q0[s] = *(const bf16x8*)(qa + s*32);
            q1[s] = *(const bf16x8*)(qb + s*32);
        }
    }

    float denw0 = 0.f, denw1 = 0.f;
    const u16* kbase = Kp + ((size_t)bh * NSEQ + n0) * MP;

    for (int qt = 0; qt < 4; ++qt) {
        __syncthreads();
        for (int i = t; i < 1152; i += 256) {
            int rr = i / 36, cc = i - rr * 36;
            *(uint4*)&R1s[rr*296 + cc*8] =
                *(const uint4*)(kbase + (size_t)(qt*32 + rr) * MP + cc*8);
        }
        __syncthreads();
        #pragma unroll
        for (int jj = 0; jj < 2; ++jj) {
            int jt = qt*2 + jj;
            #pragma unroll
            for (int itx = 0; itx < 2; ++itx) {
                int it = itx ? it1 : it0;
                if (jt <= it) {
                    f32x4 acc = (f32x4){0.f,0.f,0.f,0.f};
                    #pragma unroll
                    for (int s = 0; s < 9; ++s) {
                        bf16x8 kf = *(const bf16x8*)&R1s[(jj*16 + l16)*296 + s*32 + quad*8];
                        acc = __builtin_amdgcn_mfma_f32_16x16x32_bf16(
                            kf, itx ? q1[s] : q0[s], acc, 0, 0, 0);
                    }
                    int ig = it*16 + l16;
                    float rs = 0.f;
                    #pragma unroll
                    for (int r = 0; r < 4; ++r) {
                        int jg = jt*16 + quad*4 + r;
                        float pv = (jg <= ig) ? acc[r] : 0.f;
                        rs += pv;
                        R2s[ig*136 + jg] = f2b(pv);
                    }
                    if (itx) denw1 += rs; else denw0 += rs;
                }
            }
        }
    }

    __syncthreads();
    // stage VT (transposed V) into R1
    {
        int d0 = (t >> 5) * 8, nb = (t & 31) * 4;
        const u16* vb2 = Vb + ((size_t)(b*NSEQ + n0 + nb)) * DM + h*DH + d0;
        uint4 r0 = *(const uint4*)(vb2);
        uint4 r1 = *(const uint4*)(vb2 + DM);
        uint4 r2 = *(const uint4*)(vb2 + 2*DM);
        uint4 r3 = *(const uint4*)(vb2 + 3*DM);
        const u32* a0 = (const u32*)&r0; const u32* a1 = (const u32*)&r1;
        const u32* a2 = (const u32*)&r2; const u32* a3 = (const u32*)&r3;
        #pragma unroll
        for (int e = 0; e < 8; ++e) {
            u32 w0 = a0[e>>1], w1 = a1[e>>1], w2 = a2[e>>1], w3 = a3[e>>1];
            u32 lo2, hi2;
            if (e & 1) { lo2 = (w0 >> 16) | (w1 & 0xFFFF0000u); hi2 = (w2 >> 16) | (w3 & 0xFFFF0000u); }
            else       { lo2 = (w0 & 0xFFFFu) | (w1 << 16);     hi2 = (w2 & 0xFFFFu) | (w3 << 16); }
            uint2 uu; uu.x = lo2; uu.y = hi2;
            *(uint2*)&R1s[(d0 + e)*136 + nb] = uu;
        }
    }
    __syncthreads();

    // PV: out[i][d] += P[i][j] * VT[d][j]
    f32x4 pacc[2][4];
    #pragma unroll
    for (int i = 0; i < 2; ++i)
        #pragma unroll
        for (int j = 0; j < 4; ++j) pacc[i][j] = (f32x4){0.f,0.f,0.f,0.f};
    int ns0 = (it0 + 2) >> 1, ns1 = (it1 + 2) >> 1;
    #pragma unroll
    for (int ks = 0; ks < 4; ++ks) {
        bool u0 = ks < ns0, u1 = ks < ns1;
        bf16x8 p0 = {}, p1 = {};
        if (u0) p0 = *(const bf16x8*)&R2s[(it0*16 + l16)*136 + ks*32 + quad*8];
        if (u1) p1 = *(const bf16x8*)&R2s[(it1*16 + l16)*136 + ks*32 + quad*8];
        #pragma unroll
        for (int ct = 0; ct < 4; ++ct) {
            bf16x8 vf = *(const bf16x8*)&R1s[(ct*16 + l16)*136 + ks*32 + quad*8];
            if (u0) pacc[0][ct] = __builtin_amdgcn_mfma_f32_16x16x32_bf16(p0, vf, pacc[0][ct], 0, 0, 0);
            if (u1) pacc[1][ct] = __builtin_amdgcn_mfma_f32_16x16x32_bf16(p1, vf, pacc[1][ct], 0, 0, 0);
        }
    }

    // carry: out[i][d] += Q[i][m] * S^T[d][m], hi then lo pass
    f32x4 cacc[2][4];
    #pragma unroll
    for (int i = 0; i < 2; ++i)
        #pragma unroll
        for (int j = 0; j < 4; ++j) cacc[i][j] = (f32x4){0.f,0.f,0.f,0.f};
    const u32* spw = (const u32*)Sp + (size_t)bhc * SROW;
    #pragma unroll
    for (int pass = 0; pass < 2; ++pass) {
        __syncthreads();
        for (int i = t; i < 4608; i += 256) {
            int rr = i / 72, cc = i - rr * 72;
            uint4 v = *(const uint4*)(spw + (size_t)rr * MP + cc*4);
            u32 lo2, hi2;
            if (pass) { lo2 = (v.x >> 16) | (v.y & 0xFFFF0000u); hi2 = (v.z >> 16) | (v.w & 0xFFFF0000u); }
            else      { lo2 = (v.x & 0xFFFFu) | (v.y << 16);     hi2 = (v.z & 0xFFFFu) | (v.w << 16); }
            uint2 uu; uu.x = lo2; uu.y = hi2;
            *(uint2*)&R2s[rr*296 + cc*4] = uu;
        }
        __syncthreads();
        #pragma unroll
        for (int s = 0; s < 9; ++s)
            #pragma unroll
            for (int ct = 0; ct < 4; ++ct) {
                bf16x8 sf = *(const bf16x8*)&R2s[(ct*16 + l16)*296 + s*32 + quad*8];
                cacc[0][ct] = __builtin_amdgcn_mfma_f32_16x16x32_bf16(q0[s], sf, cacc[0][ct], 0, 0, 0);
                cacc[1][ct] = __builtin_amdgcn_mfma_f32_16x16x32_bf16(q1[s], sf, cacc[1][ct], 0, 0, 0);
            }
    }

    // den carry: q . (z_prefix + CEPS), scalar (zc fp32 from row 64)
    float dc0 = 0.f, dc1 = 0.f;
    {
        const float* zc = Sp + (size_t)bhc * SROW + (size_t)64 * MP + quad*8;
        #pragma unroll
        for (int s = 0; s < 9; ++s) {
            f32x4 za = *(const f32x4*)(zc + s*32);
            f32x4 zb = *(const f32x4*)(zc + s*32 + 4);
            #pragma unroll
            for (int e = 0; e < 4; ++e) {
                dc0 += (float)q0[s][e] * za[e];
                dc0 += (float)q0[s][e+4] * zb[e];
                dc1 += (float)q1[s][e] * za[e];
                dc1 += (float)q1[s][e+4] * zb[e];
            }
        }
    }
    dc0 += __shfl_xor(dc0, 16, 64); dc0 += __shfl_xor(dc0, 32, 64);
    dc1 += __shfl_xor(dc1, 16, 64); dc1 += __shfl_xor(dc1, 32, 64);
    denw0 += __shfl_xor(denw0, 16, 64); denw0 += __shfl_xor(denw0, 32, 64);
    denw1 += __shfl_xor(denw1, 16, 64); denw1 += __shfl_xor(denw1, 32, 64);
    float den0 = denw0 + dc0, den1 = denw1 + dc1;

    // output
    u16* ab = attn + ((size_t)(b*NSEQ + n0)) * DM + h*DH;
    #pragma unroll
    for (int itx = 0; itx < 2; ++itx) {
        int it = itx ? it1 : it0;
        float dv = itx ? den1 : den0;
        #pragma unroll
        for (int r = 0; r < 4; ++r) {
            float deno = __shfl(dv, (lane & 48) + quad*4 + r, 64);
            int row = it*16 + quad*4 + r;
            #pragma unroll
            for (int ct = 0; ct < 4; ++ct) {
                float ov = (pacc[itx][ct][r] + cacc[itx][ct][r]) / deno;
                ab[(size_t)row * DM + ct*16 + l16] = f2b(ov);
            }
        }
    }
}

// ---------------------------------------------------------------------------
extern "C" void kernel_launch(void* const* d_in, const int* in_sizes, int n_in,
                              void* d_out, int out_size, void* d_ws, size_t ws_size,
                              hipStream_t stream)
{
    (void)n_in; (void)out_size; (void)ws_size;
    const void* x  = d_in[0];
    const void* Wq = d_in[1]; const void* bq = d_in[2];
    const void* Wk = d_in[3]; const void* bk = d_in[4];
    const void* Wv = d_in[5]; const void* bv = d_in[6];
    const void* Wo = d_in[7]; const void* bo = d_in[8];
    const void* proj = d_in[9];

    char* ws = (char*)d_ws;
    size_t off = 0;
    auto alloc = [&](size_t bytes) -> char* {
        char* p = ws + off; off += (bytes + 255) & ~(size_t)255; return p;
    };
    // QKf (33.5 MB, dead after feat K) overlays Sloc (76.7 MB, used after)
    size_t qkfBytes  = (size_t)NROWS * DM * 4;
    size_t slocBytes = (size_t)(B_ * H_ * NC) * SROW * 4;
    char*  ov0  = alloc(slocBytes > qkfBytes ? slocBytes : qkfBytes);
    float* QKf  = (float*)ov0;
    float* Sloc = (float*)ov0;
    u16*   Vb   = (u16*)alloc((size_t)NROWS * DM * 2);
    u16*   Qp   = (u16*)alloc((size_t)NHROWS * MP * 2);
    u16*   Kp   = (u16*)alloc((size_t)NHROWS * MP * 2);
    u16*   projC= (u16*)alloc((size_t)MP * DH * 2);
    u16*   Wb   = (u16*)alloc((size_t)DM * DM * 2);
    u16*   bqb  = (u16*)alloc(DM * 2);
    u16*   bkb  = (u16*)alloc(DM * 2);
    u16*   bvb  = (u16*)alloc(DM * 2);
    u16*   bob  = (u16*)alloc(DM * 2);
    u32*   flags= (u32*)alloc(16 * 4);
    u32*   gmax = (u32*)alloc(256);
    u32*   gpart= (u32*)alloc(256 * 4);
    char*  xatt = alloc((size_t)NROWS * DM * 2);
    u16*   xb   = (u16*)xatt;    // alias: xb dead after gemm K
    u16*   attn = (u16*)xatt;    // scan writes afterwards

    const int nW = DM * DM, nX = NROWS * DM;
    dim3 gg(NROWS / 128, DM / 128);

    DetectArgs da;
    for (int i = 0; i < 10; ++i) {
        int n = in_sizes[i];
        int nwords = n / 2; if (nwords > 4096) nwords = 4096;
        da.p[i] = (const u32*)d_in[i];
        da.nw[i] = nwords;
    }
    detect_all<<<10, 256, 0, stream>>>(da, flags);

    prep2<<<(MP * DH + 255) / 256, 256, 0, stream>>>(proj, projC, gpart, gmax, flags + 9);
    conv_kernel<<<(nX + 2047) / 2048, 256, 0, stream>>>(x, xb, nX, flags + 0);
    conv_kernel<<<1, 256, 0, stream>>>(bq, bqb, DM, flags + 2);
    conv_kernel<<<1, 256, 0, stream>>>(bk, bkb, DM, flags + 4);
    conv_kernel<<<1, 256, 0, stream>>>(bv, bvb, DM, flags + 6);
    conv_kernel<<<1, 256, 0, stream>>>(bo, bob, DM, flags + 8);

    conv_kernel<<<(nW + 2047) / 2048, 256, 0, stream>>>(Wv, Wb, nW, flags + 5);
    gemm_nt<1><<<gg, 256, 0, stream>>>(xb, Wb, bvb, Vb);

    conv_kernel<<<(nW + 2047) / 2048, 256, 0, stream>>>(Wq, Wb, nW, flags + 1);
    gemm_nt<0><<<gg, 256, 0, stream>>>(xb, Wb, bqb, QKf);
    feat_mfma<0><<<NHROWS / 64, 256, 0, stream>>>(QKf, projC, Qp, gpart, gmax);

    conv_kernel<<<(nW + 2047) / 2048, 256, 0, stream>>>(Wk, Wb, nW, flags + 3);
    gemm_nt<0><<<gg, 256, 0, stream>>>(xb, Wb, bkb, QKf);
    feat_mfma<1><<<NHROWS / 64, 256, 0, stream>>>(QKf, projC, Kp, gpart, gmax);
    gmax_reduce<<<1, 256, 0, stream>>>(gpart, gmax);
    feat_mfma<2><<<NHROWS / 64, 256, 0, stream>>>(QKf, projC, Kp, gpart, gmax);

    // MFMA chunk-parallel causal scan
    chunk_ST<<<B_ * H_ * NC, 256, 0, stream>>>(Kp, Vb, Sloc);
    chunk_prefix<<<(B_ * H_ * SROW) / 256, 256, 0, stream>>>(Sloc);
    scan_mfma<<<B_ * H_ * NC, 256, 0, stream>>>(Qp, Kp, Vb, Sloc, attn);

    conv_kernel<<<(nW + 2047) / 2048, 256, 0, stream>>>(Wo, Wb, nW, flags + 7);
    // OUTPUT IS FP32 (reference's output dtype, per harness instructions).
    gemm_nt<0><<<gg, 256, 0, stream>>>(attn, Wb, bob, d_out);
}